// Round 4
// baseline (306.476 us; speedup 1.0000x reference)
//
#include <hip/hip_runtime.h>
#include <hip/hip_bf16.h>
#include <stdint.h>

#define B_   2
#define T_   2048
#define C_   2048
#define NH_  16
#define NKV_ 4
#define D_   128
#define NREP_ 4

typedef __attribute__((ext_vector_type(8))) short bf16x8;
typedef __attribute__((ext_vector_type(4))) float f32x4;

__device__ inline short f2bs(float f) {
    __hip_bfloat16 h = __float2bfloat16(f);
    return *reinterpret_cast<short*>(&h);
}

__device__ inline void gl_lds16(const __hip_bfloat16* g, __hip_bfloat16* l) {
    __builtin_amdgcn_global_load_lds(
        (const __attribute__((address_space(1))) unsigned int*)g,
        (__attribute__((address_space(3))) unsigned int*)l,
        16, 0, 0);
}

// ---------------- merged prep: all f32->bf16 converts + RoPE cos/sin table ----------------
__global__ void prep_kernel(const float* __restrict__ x,  const float* __restrict__ Wq,
                            const float* __restrict__ Wk, const float* __restrict__ Wv,
                            const float* __restrict__ Wo,
                            __hip_bfloat16* __restrict__ xb, __hip_bfloat16* __restrict__ wcat,
                            __hip_bfloat16* __restrict__ wob, float2* __restrict__ ropeTab) {
    int tid = blockIdx.x * blockDim.x + threadIdx.x;
    const int CVT_THREADS = 4718592;
    if (tid < CVT_THREADS) {
        int i4 = tid * 4;
        const float* src;
        __hip_bfloat16* dst;
        int off;
        if (i4 < 8388608)       { src = x;  dst = xb;             off = i4; }
        else if (i4 < 12582912) { src = Wq; dst = wcat;           off = i4 - 8388608; }
        else if (i4 < 13631488) { src = Wk; dst = wcat + 4194304; off = i4 - 12582912; }
        else if (i4 < 14680064) { src = Wv; dst = wcat + 5242880; off = i4 - 13631488; }
        else                    { src = Wo; dst = wob;            off = i4 - 14680064; }
        float4 v = *reinterpret_cast<const float4*>(src + off);
        short4 o;
        o.x = f2bs(v.x); o.y = f2bs(v.y); o.z = f2bs(v.z); o.w = f2bs(v.w);
        *reinterpret_cast<short4*>(dst + off) = o;
    } else {
        int e = tid - CVT_THREADS;
        if (e < 131072) {
            int t = e >> 6, p = e & 63;
            float inv = __expf(-(float)p * (9.210340371976184f / 64.0f));  // 10000^(-p/64)
            float ang = (float)t * inv;
            ropeTab[e] = make_float2(cosf(ang), sinf(ang));
        }
    }
}

// ---------------- 256x256xK64 8-phase bf16 GEMM (T1+T2+T3+T4+T5), C = A @ B^T ----------------
// Plain-HIP port of the m201 template: 512 thr (8 waves 2Mx4N), 128KiB LDS double
// buffer, per-wave 128x64 C, 4 phases/K-step of {ds_read subtile | stage half-tile |
// bar | lgkmcnt(0) | setprio 16xMFMA | bar}, counted vmcnt(6) once per K-step.
// LDS XOR-swizzle (byte ^= (row&7)<<4) applied on the READ and on the pre-swizzled
// global SOURCE (gl_lds dest stays linear) per rule #21.
// Staging slot liveness: A-halves freed after ph2, B-halves after ph1. Schedule:
//   ph0: A1 of step u+1 -> buf(1-p) | ph2: B0 of u+2 -> buf p | ph3: A0 + B1 of u+2.
// vmcnt(6) at ph3 leaves exactly those 3 half-tiles in flight; everything the next
// K-step reads is confirmed landed. Last two K-steps peeled (drain vmcnt 0).
// MODE 0: f32 C store (output proj). MODE 1: fused RoPE + q/k/vT scatter (a 256-col
// tile = exactly 2 heads; head = wn>>1, wave-uniform; rope partner = lane^1).
template <int MODE, int NTN>
__global__ __launch_bounds__(512, 2) void gemm256(
    const __hip_bfloat16* __restrict__ A,
    const __hip_bfloat16* __restrict__ Bm,
    const float2* __restrict__ ropeTab,
    __hip_bfloat16* __restrict__ qo,
    __hip_bfloat16* __restrict__ ko,
    __hip_bfloat16* __restrict__ vT,
    float* __restrict__ Cout) {
    constexpr int K = 2048;
    constexpr int NT = K / 64;       // 32 K-steps
    extern __shared__ char lds[];    // [A: 2buf x 2half x 16KB][B: same] = 128 KiB

    const int tid = threadIdx.x;
    const int lane = tid & 63;
    const int wid = tid >> 6;
    const int wm = wid >> 2, wn = wid & 3;
    const int q16 = lane >> 4, r16 = lane & 15;

    // T1: XCD-aware swizzle (grid % 8 == 0 for both instantiations)
    const int cpx = (int)gridDim.x >> 3;
    const int bs = ((int)blockIdx.x & 7) * cpx + ((int)blockIdx.x >> 3);
    const int tm = bs / NTN, tn = bs % NTN;
    const int rmA = tm * 256, rmB = tn * 256;

    char* const aBuf0 = lds + wm * 16384;
    char* const aBuf1 = lds + 32768 + wm * 16384;
    char* const bBuf0 = lds + 65536 + (wn >> 1) * 16384;
    char* const bBuf1 = lds + 65536 + 32768 + (wn >> 1) * 16384;

    const int sw  = (r16 & 7) << 4;            // T2 swizzle term (bits 4-6)
    const int cS0 = (q16 << 4) ^ sw;           // k-slice 0 byte col
    const int cS1 = (64 | (q16 << 4)) ^ sw;    // k-slice 1 byte col
    const int rA128 = r16 * 128;
    const int rB128 = ((wn & 1) * 64 + r16) * 128;

    f32x4 acc[8][4] = {};
    bf16x8 aF[4][2], bF[2][2][2];

#define STG(Mp, rowbase, kstep, ldsoff)                                              \
    { _Pragma("unroll") for (int li = 0; li < 2; li++) {                             \
        const int L_ = li * 8192 + tid * 16;                                         \
        const int rw_ = L_ >> 7;                                                     \
        const int cb_ = (L_ & 127) ^ ((rw_ & 7) << 4);                               \
        gl_lds16(Mp + (size_t)((rowbase) + rw_) * K + (kstep) * 64 + (cb_ >> 1),     \
                 (__hip_bfloat16*)(lds + (ldsoff) + L_));                            \
    } }
#define RDA(base, a)                                                                 \
    { _Pragma("unroll") for (int mi = 0; mi < 4; mi++) {                             \
        const char* p_ = (base) + (a) * 8192 + mi * 2048 + rA128;                    \
        aF[mi][0] = *(const bf16x8*)(p_ + cS0);                                      \
        aF[mi][1] = *(const bf16x8*)(p_ + cS1);                                      \
    } }
#define RDB(base, b)                                                                 \
    { _Pragma("unroll") for (int nj = 0; nj < 2; nj++) {                             \
        const char* p_ = (base) + (b) * 4096 + nj * 2048 + rB128;                    \
        bF[b][nj][0] = *(const bf16x8*)(p_ + cS0);                                   \
        bF[b][nj][1] = *(const bf16x8*)(p_ + cS1);                                   \
    } }
#define MM(a, b)                                                                     \
    { _Pragma("unroll") for (int mi = 0; mi < 4; mi++)                               \
      _Pragma("unroll") for (int nj = 0; nj < 2; nj++) {                             \
        acc[(a)*4+mi][(b)*2+nj] = __builtin_amdgcn_mfma_f32_16x16x32_bf16(           \
            aF[mi][0], bF[(b)][nj][0], acc[(a)*4+mi][(b)*2+nj], 0, 0, 0);            \
        acc[(a)*4+mi][(b)*2+nj] = __builtin_amdgcn_mfma_f32_16x16x32_bf16(           \
            aF[mi][1], bF[(b)][nj][1], acc[(a)*4+mi][(b)*2+nj], 0, 0, 0);            \
    } }
#define BAR  __builtin_amdgcn_s_barrier()
#define LGK0 asm volatile("s_waitcnt lgkmcnt(0)" ::: "memory")
#define VM6  asm volatile("s_waitcnt vmcnt(6)" ::: "memory")
#define VM0  asm volatile("s_waitcnt vmcnt(0)" ::: "memory")
#define PRIO_MM(a, b)                                                                \
    __builtin_amdgcn_s_setprio(1); MM(a, b); __builtin_amdgcn_s_setprio(0)
#define STEP(AB_, BB_, S0_, S2_, S3a_, S3b_, VMW_)                                   \
    RDA(AB_, 0); RDB(BB_, 0); S0_;                                                   \
    BAR; LGK0; PRIO_MM(0, 0); BAR;                                                   \
    RDB(BB_, 1);                                                                     \
    BAR; LGK0; PRIO_MM(0, 1); BAR;                                                   \
    RDA(AB_, 1); S2_;                                                                \
    BAR; LGK0; PRIO_MM(1, 0); BAR;                                                   \
    S3a_; S3b_;                                                                      \
    BAR; LGK0; PRIO_MM(1, 1); VMW_; BAR;

    // prologue: step0 fully (first 8 loads), then step1's B0/A0/B1 (6 loads)
    STG(A,  rmA,       0, 0);
    STG(A,  rmA + 128, 0, 16384);
    STG(Bm, rmB,       0, 65536);
    STG(Bm, rmB + 128, 0, 65536 + 16384);
    STG(A,  rmA,       1, 32768);
    STG(Bm, rmB,       1, 65536 + 32768);
    STG(Bm, rmB + 128, 1, 65536 + 32768 + 16384);
    VM6; BAR;

    for (int u = 0; u < NT - 2; u += 2) {
        STEP(aBuf0, bBuf0,
             STG(A,  rmA + 128, u + 1, 32768 + 16384),
             STG(Bm, rmB,       u + 2, 65536),
             STG(A,  rmA,       u + 2, 0),
             STG(Bm, rmB + 128, u + 2, 65536 + 16384),
             VM6)
        STEP(aBuf1, bBuf1,
             STG(A,  rmA + 128, u + 2, 16384),
             STG(Bm, rmB,       u + 3, 65536 + 32768),
             STG(A,  rmA,       u + 3, 32768),
             STG(Bm, rmB + 128, u + 3, 65536 + 32768 + 16384),
             VM6)
    }
    // peeled: step NT-2 (stage only A1 of NT-1, then drain), step NT-1 (no staging)
    STEP(aBuf0, bBuf0,
         STG(A, rmA + 128, NT - 1, 32768 + 16384),
         ((void)0), ((void)0), ((void)0),
         VM0)
    STEP(aBuf1, bBuf1, ((void)0), ((void)0), ((void)0), ((void)0), ((void)0))

#undef STEP
#undef PRIO_MM
#undef VM0
#undef VM6
#undef LGK0
#undef BAR
#undef MM
#undef RDB
#undef RDA
#undef STG

    if constexpr (MODE == 0) {
        constexpr int N = NTN * 256;
        float* const cbase = Cout + (size_t)(rmA + wm * 128) * N + tn * 256 + wn * 64 + r16;
#pragma unroll
        for (int Ai = 0; Ai < 8; Ai++)
#pragma unroll
            for (int r = 0; r < 4; r++) {
                float* dst = cbase + (size_t)(Ai * 16 + q16 * 4 + r) * N;
#pragma unroll
                for (int Bi = 0; Bi < 4; Bi++)
                    dst[Bi * 16] = acc[Ai][Bi][r];
            }
    } else {
        const int hb = tn * 2 + (wn >> 1);   // 0..15 q | 16..19 k | 20..23 v (wave-uniform)
        const float sgn = (r16 & 1) ? 1.0f : -1.0f;
#pragma unroll
        for (int Ai = 0; Ai < 8; Ai++)
#pragma unroll
            for (int r = 0; r < 4; r++) {
                const int m = rmA + wm * 128 + Ai * 16 + q16 * 4 + r;
                const int bb = m >> 11, t = m & 2047;
                if (hb < 20) {  // q or k: RoPE then scatter
                    const float2* tabRow = ropeTab + t * 64;
                    __hip_bfloat16* dst = (hb < 16)
                        ? qo + ((size_t)(bb * NH_ + hb) * T_ + t) * D_
                        : ko + ((size_t)(bb * NKV_ + (hb - 16)) * T_ + t) * D_;
#pragma unroll
                    for (int Bi = 0; Bi < 4; Bi++) {
                        const int dloc = (wn & 1) * 64 + Bi * 16 + r16;
                        float v = acc[Ai][Bi][r];
                        float prt = __shfl_xor(v, 1);
                        float2 cs = tabRow[dloc >> 1];
                        dst[dloc] = __float2bfloat16(fmaf(prt * sgn, cs.y, v * cs.x));
                    }
                } else {        // v: transposed (d, t) store
                    __hip_bfloat16* dst = vT + (size_t)(bb * NKV_ + (hb - 20)) * D_ * T_ + t;
#pragma unroll
                    for (int Bi = 0; Bi < 4; Bi++) {
                        const int dloc = (wn & 1) * 64 + Bi * 16 + r16;
                        dst[(size_t)dloc * T_] = __float2bfloat16(acc[Ai][Bi][r]);
                    }
                }
            }
    }
}

// ---------------- flash attention, GQA-cooperative, split-s flash-decoding ----------------
__global__ __launch_bounds__(256, 3) void attn_kernel(const __hip_bfloat16* __restrict__ Q,
                                                      const __hip_bfloat16* __restrict__ Kt,
                                                      const __hip_bfloat16* __restrict__ Vt,
                                                      __hip_bfloat16* __restrict__ Ao,
                                                      float* __restrict__ O0,
                                                      float* __restrict__ O1,
                                                      float* __restrict__ l0p,
                                                      float* __restrict__ l1p) {
    __shared__ __hip_bfloat16 Ks[2][4096];   // 8 chunks x 512 shorts, x2 buffers
    __shared__ __hip_bfloat16 Vs[2][4096];
    __shared__ __hip_bfloat16 Pl[4][1280];   // per-wave 2 tiles x (16q x 32s, stride 40)

    const int lane = threadIdx.x & 63, wv = threadIdx.x >> 6;
    const int bg = blockIdx.y;                              // 0..7 : (b,g)
    const int u  = (int)blockIdx.x;                         // 0..95 work unit
    int tb, nIt, sIdx;
    if (u < 32)      { tb = u;      nIt = tb + 1;      sIdx = -1; }  // whole row range
    else if (u < 64) { tb = u;      nIt = 32;          sIdx = 0;  }  // s in [0,1024)
    else             { tb = u - 32; nIt = tb + 1 - 32; sIdx = 1;  }  // s in [1024, ...)
    const int sBase = (sIdx == 1) ? 1024 : 0;
    const int b = bg >> 2, g = bg & 3;
    const int h = g * 4 + wv;                               // this wave's q-head
    const int t0 = tb * 32;
    const int q16 = lane >> 4, r16 = lane & 15;

    const __hip_bfloat16* qh = Q + ((size_t)((b * NH_ + h) * T_) + t0) * D_;
    const __hip_bfloat16* kh = Kt + (size_t)(b * NKV_ + g) * T_ * D_;
    const __hip_bfloat16* vh = Vt + (size_t)(b * NKV_ + g) * D_ * T_;

    bf16x8 bqA[4], bqB[4];
#pragma unroll
    for (int kk = 0; kk < 4; kk++) {
        bqA[kk] = *reinterpret_cast<const bf16x8*>(qh + (size_t)r16 * D_ + kk * 32 + q16 * 8);
        bqB[kk] = *reinterpret_cast<const bf16x8*>(qh + (size_t)(16 + r16) * D_ + kk * 32 + q16 * 8);
    }

    float liA = 0.f, liB = 0.f;
    f32x4 oA[8], oB[8];
#pragma unroll
    for (int d = 0; d < 8; d++) {
        oA[d] = (f32x4){0.f, 0.f, 0.f, 0.f};
        oB[d] = (f32x4){0.f, 0.f, 0.f, 0.f};
    }

    const float SCL2 = 0.088388347648318447f * 1.4426950408889634f;  // (1/sqrt(D)) * log2(e)
    const int tqA = t0 + r16;
    const int tqB = t0 + 16 + r16;

    const __hip_bfloat16* gK = kh + (size_t)((wv & 1) * 16 + r16) * D_ + q16 * 8;
    const __hip_bfloat16* gV = vh + (size_t)(((wv - 2) * 4) * 16 + r16) * T_ + q16 * 8;

#define STAGE(bufi, s0_)                                                        \
    do {                                                                        \
        if (wv < 2) {                                                           \
            const __hip_bfloat16* gp = gK + (size_t)(s0_) * D_;                 \
            __hip_bfloat16* lp = &Ks[bufi][(wv * 4) * 512] + lane * 8;          \
            gl_lds16(gp,      lp);                                              \
            gl_lds16(gp + 32, lp + 512);                                        \
            gl_lds16(gp + 64, lp + 1024);                                      \
            gl_lds16(gp + 96, lp + 1536);                                      \
        } else {                                                                \
            const __hip_bfloat16* gp = gV + (s0_);                              \
            __hip_bfloat16* lp = &Vs[bufi][((wv - 2) * 4) * 512] + lane * 8;    \
            gl_lds16(gp,                      lp);                              \
            gl_lds16(gp + (size_t)16 * T_,    lp + 512);                        \
            gl_lds16(gp + (size_t)32 * T_,    lp + 1024);                      \
            gl_lds16(gp + (size_t)48 * T_,    lp + 1536);                      \
        }                                                                       \
    } while (0)

    STAGE(0, sBase);

    for (int j = 0; j < nIt; j++) {
        const int s0 = sBase + j * 32;
        const int cur = j & 1;
        __syncthreads();  // staging of `cur` complete; buffer `cur^1` free
        if (j + 1 < nIt) STAGE(cur ^ 1, s0 + 32);

        f32x4 sc0A = (f32x4){0.f, 0.f, 0.f, 0.f};
        f32x4 sc1A = (f32x4){0.f, 0.f, 0.f, 0.f};
        f32x4 sc0B = (f32x4){0.f, 0.f, 0.f, 0.f};
        f32x4 sc1B = (f32x4){0.f, 0.f, 0.f, 0.f};
        {
            bf16x8 ak[4];
#pragma unroll
            for (int kk = 0; kk < 4; kk++)
                ak[kk] = *reinterpret_cast<const bf16x8*>(&Ks[cur][kk * 512] + lane * 8);
#pragma unroll
            for (int kk = 0; kk < 4; kk++) {
                sc0A = __builtin_amdgcn_mfma_f32_16x16x32_bf16(ak[kk], bqA[kk], sc0A, 0, 0, 0);
                sc0B = __builtin_amdgcn_mfma_f32_16x16x32_bf16(ak[kk], bqB[kk], sc0B, 0, 0, 0);
            }
#pragma unroll
            for (int kk = 0; kk < 4; kk++)
                ak[kk] = *reinterpret_cast<const bf16x8*>(&Ks[cur][(4 + kk) * 512] + lane * 8);
#pragma unroll
            for (int kk = 0; kk < 4; kk++) {
                sc1A = __builtin_amdgcn_mfma_f32_16x16x32_bf16(ak[kk], bqA[kk], sc1A, 0, 0, 0);
                sc1B = __builtin_amdgcn_mfma_f32_16x16x32_bf16(ak[kk], bqB[kk], sc1B, 0, 0, 0);
            }
        }

        ushort4 w0A, w1A, w0B, w1B;
        float psA = 0.f, psB = 0.f;
        if (s0 + 32 > t0) {  // diagonal iteration: causal mask (wave-uniform branch)
#pragma unroll
            for (int r = 0; r < 4; r++) {
                int s_a = s0 + q16 * 4 + r;
                float pa0 = (s_a <= tqA)      ? __builtin_amdgcn_exp2f(sc0A[r] * SCL2) : 0.f;
                float pa1 = (s_a + 16 <= tqA) ? __builtin_amdgcn_exp2f(sc1A[r] * SCL2) : 0.f;
                float pb0 = (s_a <= tqB)      ? __builtin_amdgcn_exp2f(sc0B[r] * SCL2) : 0.f;
                float pb1 = (s_a + 16 <= tqB) ? __builtin_amdgcn_exp2f(sc1B[r] * SCL2) : 0.f;
                psA += pa0 + pa1;
                psB += pb0 + pb1;
                ((unsigned short*)&w0A)[r] = (unsigned short)f2bs(pa0);
                ((unsigned short*)&w1A)[r] = (unsigned short)f2bs(pa1);
                ((unsigned short*)&w0B)[r] = (unsigned short)f2bs(pb0);
                ((unsigned short*)&w1B)[r] = (unsigned short)f2bs(pb1);
            }
        } else {  // interior iteration
#pragma unroll
            for (int r = 0; r < 4; r++) {
                float pa0 = __builtin_amdgcn_exp2f(sc0A[r] * SCL2);
                float pa1 = __builtin_amdgcn_exp2f(sc1A[r] * SCL2);
                float pb0 = __builtin_amdgcn_exp2f(sc0B[r] * SCL2);
                float pb1 = __builtin_amdgcn_exp2f(sc1B[r] * SCL2);
                psA += pa0 + pa1;
                psB += pb0 + pb1;
                ((unsigned short*)&w0A)[r] = (unsigned short)f2bs(pa0);
                ((unsigned short*)&w1A)[r] = (unsigned short)f2bs(pa1);
                ((unsigned short*)&w0B)[r] = (unsigned short)f2bs(pb0);
                ((unsigned short*)&w1B)[r] = (unsigned short)f2bs(pb1);
            }
        }
        liA += psA;
        liB += psB;

        *reinterpret_cast<ushort4*>(&Pl[wv][r16 * 40 + q16 * 4]) = w0A;
        *reinterpret_cast<ushort4*>(&Pl[wv][r16 * 40 + 16 + q16 * 4]) = w1A;
        *reinterpret_cast<ushort4*>(&Pl[wv][640 + r16 * 40 + q16 * 4]) = w0B;
        *reinterpret_cast<ushort4*>(&Pl[wv][640 + r16 * 40 + 16 + q16 * 4]) = w1B;
        asm volatile("s_waitcnt lgkmcnt(0)" ::: "memory");
        bf16x8 pfA = *reinterpret_cast<const bf16x8*>(&Pl[wv][r16 * 40 + q16 * 8]);
        bf16x8 pfB = *reinterpret_cast<const bf16x8*>(&Pl[wv][640 + r16 * 40 + q16 * 8]);

#pragma unroll
        for (int d = 0; d < 8; d++) {
            bf16x8 bv = *reinterpret_cast<const bf16x8*>(&Vs[cur][d * 512] + lane * 8);
            oA[d] = __builtin_amdgcn_mfma_f32_16x16x32_bf16(pfA, bv, oA[d], 0, 0, 0);
            oB[d] = __builtin_amdgcn_mfma_f32_16x16x32_bf16(pfB, bv, oB[d], 0, 0, 0);
        }
    }

    liA += __shfl_xor(liA, 16);
    liA += __shfl_xor(liA, 32);
    liB += __shfl_xor(liB, 16);
    liB += __shfl_xor(liB, 32);

    if (sIdx < 0) {
#pragma unroll
        for (int r = 0; r < 4; r++) {
            float lrA = __shfl(liA, q16 * 4 + r, 16);
            float lrB = __shfl(liB, q16 * 4 + r, 16);
            float invA = 1.0f / lrA;
            float invB = 1.0f / lrB;
            int tA = t0 + q16 * 4 + r;
            __hip_bfloat16* dstA = Ao + (size_t)(b * T_ + tA) * C_ + h * D_ + r16;
            __hip_bfloat16* dstB = dstA + (size_t)16 * C_;
#pragma unroll
            for (int d = 0; d < 8; d++) {
                dstA[d * 16] = __float2bfloat16(oA[d][r] * invA);
                dstB[d * 16] = __float2bfloat16(oB[d][r] * invB);
            }
        }
    } else {
        float* Os = (sIdx == 0) ? O0 : O1;
        float* ls = (sIdx == 0) ? l0p : l1p;
        const size_t rb = (size_t)(b * NH_ + h) * 1024 + (size_t)(t0 - 1024);
        if (q16 == 0) {
            ls[rb + r16]      = liA;
            ls[rb + 16 + r16] = liB;
        }
#pragma unroll
        for (int r = 0; r < 4; r++) {
            int rowl = q16 * 4 + r;
            float* dA = Os + (rb + rowl) * 128 + r16;
            float* dB = Os + (rb + 16 + rowl) * 128 + r16;
#pragma unroll
            for (int d = 0; d < 8; d++) {
                dA[d * 16] = oA[d][r];
                dB[d * 16] = oB[d][r];
            }
        }
    }
#undef STAGE
}

// ---------------- combine split-s partials (rows t >= 1024) ----------------
__global__ void attn_combine(const float* __restrict__ O0, const float* __restrict__ O1,
                             const float* __restrict__ l0, const float* __restrict__ l1,
                             __hip_bfloat16* __restrict__ Ao) {
    int idx = blockIdx.x * blockDim.x + threadIdx.x;   // [0, 32768*32)
    int row = idx >> 5, d4 = (idx & 31) << 2;
    int bh = row >> 10, tl = row & 1023;
    int b = bh >> 4, h = bh & 15;
    float inv = 1.0f / (l0[row] + l1[row]);
    float4 a = *reinterpret_cast<const float4*>(O0 + (size_t)row * 128 + d4);
    float4 c = *reinterpret_cast<const float4*>(O1 + (size_t)row * 128 + d4);
    short4 o;
    o.x = f2bs((a.x + c.x) * inv);
    o.y = f2bs((a.y + c.y) * inv);
    o.z = f2bs((a.z + c.z) * inv);
    o.w = f2bs((a.w + c.w) * inv);
    *reinterpret_cast<short4*>(Ao + (size_t)(b * T_ + 1024 + tl) * C_ + h * D_ + d4) = o;
}

// ---------------- launch ----------------
extern "C" void kernel_launch(void* const* d_in, const int* in_sizes, int n_in,
                              void* d_out, int out_size, void* d_ws, size_t ws_size,
                              hipStream_t stream) {
    const float* x  = (const float*)d_in[0];
    const float* Wq = (const float*)d_in[1];
    const float* Wk = (const float*)d_in[2];
    const float* Wv = (const float*)d_in[3];
    const float* Wo = (const float*)d_in[4];
    float* out = (float*)d_out;
    char* ws = (char*)d_ws;

    __hip_bfloat16* xb   = (__hip_bfloat16*)(ws + 0);          // 16.78 MB (dead after GEMM1)
    __hip_bfloat16* wcat = (__hip_bfloat16*)(ws + 16777216);   // 12.58 MB
    float2*         ropeTab = (float2*)(ws + 29360128);        // 1.05 MB
    __hip_bfloat16* wob  = (__hip_bfloat16*)(ws + 30408704);   // 8.39 MB (live until GEMM2)
    __hip_bfloat16* qatt = (__hip_bfloat16*)(ws + 38797312);   // 16.78 MB
    __hip_bfloat16* katt = (__hip_bfloat16*)(ws + 55574528);   // 4.19 MB
    __hip_bfloat16* vT   = (__hip_bfloat16*)(ws + 59768832);   // 4.19 MB
    __hip_bfloat16* aout = (__hip_bfloat16*)(ws + 63963136);   // 16.78 MB
    float* O0 = (float*)(ws + 0);                              // overlays dead xb
    float* O1 = (float*)(ws + 80740352);                       // 16.78 MB
    float* l0 = (float*)(ws + 97517568);                       // 128 KB
    float* l1 = (float*)(ws + 97648640);                       // 128 KB (end ~97.8 MB)

    static bool s_attr_done = false;
    if (!s_attr_done) {
        hipFuncSetAttribute(reinterpret_cast<const void*>(&gemm256<1, 12>),
                            hipFuncAttributeMaxDynamicSharedMemorySize, 131072);
        hipFuncSetAttribute(reinterpret_cast<const void*>(&gemm256<0, 8>),
                            hipFuncAttributeMaxDynamicSharedMemorySize, 131072);
        s_attr_done = true;
    }

    const int thr = 256;
    prep_kernel<<<18944, thr, 0, stream>>>(x, Wq, Wk, Wv, Wo, xb, wcat, wob, ropeTab);

    // QKV projection + RoPE + scatter: M=4096, N=3072, K=2048, grid 16x12=192
    gemm256<1, 12><<<192, 512, 131072, stream>>>(xb, wcat, ropeTab, qatt, katt, vT, nullptr);

    attn_kernel<<<dim3(96, 8), 256, 0, stream>>>(qatt, katt, vT, aout, O0, O1, l0, l1);
    attn_combine<<<(2 * NH_ * 1024 * 32) / thr, thr, 0, stream>>>(O0, O1, l0, l1, aout);

    // Output projection: M=4096, N=2048, K=2048, grid 16x8=128
    gemm256<0, 8><<<128, 512, 131072, stream>>>(aout, wob, nullptr, nullptr, nullptr, nullptr, out);
}

// Round 5
// 293.047 us; speedup vs baseline: 1.0458x; 1.0458x over previous
//
#include <hip/hip_runtime.h>
#include <hip/hip_bf16.h>
#include <stdint.h>

#define B_   2
#define T_   2048
#define C_   2048
#define NH_  16
#define NKV_ 4
#define D_   128
#define NREP_ 4

typedef __attribute__((ext_vector_type(8))) short bf16x8;
typedef __attribute__((ext_vector_type(4))) float f32x4;

__device__ inline short f2bs(float f) {
    __hip_bfloat16 h = __float2bfloat16(f);
    return *reinterpret_cast<short*>(&h);
}

__device__ inline void gl_lds16(const __hip_bfloat16* g, __hip_bfloat16* l) {
    __builtin_amdgcn_global_load_lds(
        (const __attribute__((address_space(1))) unsigned int*)g,
        (__attribute__((address_space(3))) unsigned int*)l,
        16, 0, 0);
}

// ---------------- merged prep: all f32->bf16 converts + RoPE cos/sin table ----------------
__global__ void prep_kernel(const float* __restrict__ x,  const float* __restrict__ Wq,
                            const float* __restrict__ Wk, const float* __restrict__ Wv,
                            const float* __restrict__ Wo,
                            __hip_bfloat16* __restrict__ xb, __hip_bfloat16* __restrict__ wcat,
                            __hip_bfloat16* __restrict__ wob, float2* __restrict__ ropeTab) {
    int tid = blockIdx.x * blockDim.x + threadIdx.x;
    const int CVT_THREADS = 4718592;
    if (tid < CVT_THREADS) {
        int i4 = tid * 4;
        const float* src;
        __hip_bfloat16* dst;
        int off;
        if (i4 < 8388608)       { src = x;  dst = xb;             off = i4; }
        else if (i4 < 12582912) { src = Wq; dst = wcat;           off = i4 - 8388608; }
        else if (i4 < 13631488) { src = Wk; dst = wcat + 4194304; off = i4 - 12582912; }
        else if (i4 < 14680064) { src = Wv; dst = wcat + 5242880; off = i4 - 13631488; }
        else                    { src = Wo; dst = wob;            off = i4 - 14680064; }
        float4 v = *reinterpret_cast<const float4*>(src + off);
        short4 o;
        o.x = f2bs(v.x); o.y = f2bs(v.y); o.z = f2bs(v.z); o.w = f2bs(v.w);
        *reinterpret_cast<short4*>(dst + off) = o;
    } else {
        int e = tid - CVT_THREADS;
        if (e < 131072) {
            int t = e >> 6, p = e & 63;
            float inv = __expf(-(float)p * (9.210340371976184f / 64.0f));  // 10000^(-p/64)
            float ang = (float)t * inv;
            ropeTab[e] = make_float2(cosf(ang), sinf(ang));
        }
    }
}

// ---------------- 256xBNxK64 free-flow bf16 GEMM, C = A @ B^T ----------------
// R5 structure: dbuf LDS + counted vmcnt (never 0 in loop) + 2 compiler-scheduled
// phases per K-step. Tiles staged as K-SLICE halves (k 0-31 / 32-63) so "slice s
// confirmed" is exactly what EVERY wave needs for phase s (wave-symmetric, unlike
// row-halves). Phase: {12(8) ds_read_b128 + 32(16) MFMA, compiler interleaves with
// its own lgkmcnt; stage next tile's same slice into buf^1; vmcnt(VMN); barrier}.
// Ledger: end-A(u) in flight = {A1B1(u), A0B0(u+1)} = 2*VMN -> vmcnt(VMN) confirms
// A1B1(u) (phase B needs it); end-B(u) confirms A0B0(u+1). Staging always writes
// buf^1 while reads hit buf: no DMA-into-live-buffer race. Swizzle for 64B slice
// rows: col ^= (row&3)<<4 -> 64 lanes read 64 distinct 16B slots (conflict-free);
// global source pre-swizzled, gl_lds dest linear (rule 21).
// MODE 0: f32 C store. MODE 1: fused RoPE + q/k/vT scatter (256-col tile = 2 heads).
template <int MODE, int BN, int NTN>
__global__ __launch_bounds__(512, 2) void gemm_ff(
    const __hip_bfloat16* __restrict__ A,
    const __hip_bfloat16* __restrict__ Bm,
    const float2* __restrict__ ropeTab,
    __hip_bfloat16* __restrict__ qo,
    __hip_bfloat16* __restrict__ ko,
    __hip_bfloat16* __restrict__ vT,
    float* __restrict__ Cout) {
    constexpr int K = 2048;
    constexpr int NT = K / 64;           // 32 K-steps
    constexpr int WN = BN / 64;          // waves along N: 4 (BN256) / 2 (BN128)
    constexpr int WM = 8 / WN;           // waves along M: 2 / 4
    constexpr int RPW = 256 / WM;        // rows per wave: 128 / 64
    constexpr int MI_T = RPW / 16;       // 8 / 4
    constexpr int BSZ = BN * 64;         // B slice bytes: 16384 / 8192
    constexpr int BLOADS = BSZ / 8192;   // 2 / 1
    extern __shared__ char lds[];        // A: [buf][slice]16KB at 0; B at 65536

    const int tid = threadIdx.x;
    const int lane = tid & 63;
    const int wid = tid >> 6;
    const int wm = wid / WN, wn = wid % WN;
    const int q16 = lane >> 4, r16 = lane & 15;

    // T1: XCD-aware swizzle (grid % 8 == 0)
    const int cpx = (int)gridDim.x >> 3;
    const int bs = ((int)blockIdx.x & 7) * cpx + ((int)blockIdx.x >> 3);
    const int tm = bs / NTN, tn = bs % NTN;
    const int rmA = tm * 256, rmB = tn * BN;

    const int csw = (q16 << 4) ^ ((r16 & 3) << 4);   // frag read col within 64B row

    f32x4 acc[MI_T][4] = {};
    bf16x8 aF[MI_T], bF[4];

#define STG_A(buf_, sl_, kstep_)                                                     \
    { _Pragma("unroll") for (int li = 0; li < 2; li++) {                             \
        const int L_ = li * 8192 + tid * 16;                                         \
        const int rw_ = L_ >> 6;                                                     \
        const int cb_ = (L_ & 63) ^ ((rw_ & 3) << 4);                                \
        gl_lds16(A + (size_t)(rmA + rw_) * K + (kstep_) * 64 + (sl_) * 32 + (cb_ >> 1), \
                 (__hip_bfloat16*)(lds + (buf_) * 32768 + (sl_) * 16384 + L_));      \
    } }
#define STG_B(buf_, sl_, kstep_)                                                     \
    { _Pragma("unroll") for (int li = 0; li < BLOADS; li++) {                        \
        const int L_ = li * 8192 + tid * 16;                                         \
        const int rw_ = L_ >> 6;                                                     \
        const int cb_ = (L_ & 63) ^ ((rw_ & 3) << 4);                                \
        gl_lds16(Bm + (size_t)(rmB + rw_) * K + (kstep_) * 64 + (sl_) * 32 + (cb_ >> 1), \
                 (__hip_bfloat16*)(lds + 65536 + (buf_) * 2 * BSZ + (sl_) * BSZ + L_)); \
    } }
#define RD_A(buf_, sl_)                                                              \
    { _Pragma("unroll") for (int mi = 0; mi < MI_T; mi++)                            \
        aF[mi] = *(const bf16x8*)(lds + (buf_) * 32768 + (sl_) * 16384 +             \
                                  (wm * RPW + mi * 16 + r16) * 64 + csw); }
#define RD_B(buf_, sl_)                                                              \
    { _Pragma("unroll") for (int bi = 0; bi < 4; bi++)                               \
        bF[bi] = *(const bf16x8*)(lds + 65536 + (buf_) * 2 * BSZ + (sl_) * BSZ +     \
                                  (wn * 64 + bi * 16 + r16) * 64 + csw); }
#define MM_                                                                          \
    { __builtin_amdgcn_s_setprio(1);                                                 \
      _Pragma("unroll") for (int mi = 0; mi < MI_T; mi++)                            \
      _Pragma("unroll") for (int bi = 0; bi < 4; bi++)                               \
          acc[mi][bi] = __builtin_amdgcn_mfma_f32_16x16x32_bf16(                     \
              aF[mi], bF[bi], acc[mi][bi], 0, 0, 0);                                 \
      __builtin_amdgcn_s_setprio(0); }
#define VMC                                                                          \
    { if constexpr (BLOADS == 2) { asm volatile("s_waitcnt vmcnt(4)" ::: "memory"); } \
      else                       { asm volatile("s_waitcnt vmcnt(3)" ::: "memory"); } }
#define BAR __builtin_amdgcn_s_barrier()

    // prologue: stage tile 0 (both slices); confirm slice 0
    STG_A(0, 0, 0); STG_B(0, 0, 0);
    STG_A(0, 1, 0); STG_B(0, 1, 0);
    VMC; BAR;

    for (int u = 0; u < NT - 1; u++) {
        const int bf_ = u & 1;
        // phase A (k-slice 0)
        RD_A(bf_, 0); RD_B(bf_, 0);
        STG_A(bf_ ^ 1, 0, u + 1); STG_B(bf_ ^ 1, 0, u + 1);
        MM_;
        VMC; BAR;   // confirms A1B1(u) for phase B
        // phase B (k-slice 1)
        RD_A(bf_, 1); RD_B(bf_, 1);
        STG_A(bf_ ^ 1, 1, u + 1); STG_B(bf_ ^ 1, 1, u + 1);
        MM_;
        VMC; BAR;   // confirms A0B0(u+1)
    }
    {   // peeled last K-step (no staging; drain for slice 1)
        const int bf_ = (NT - 1) & 1;
        RD_A(bf_, 0); RD_B(bf_, 0);
        MM_;
        asm volatile("s_waitcnt vmcnt(0)" ::: "memory"); BAR;
        RD_A(bf_, 1); RD_B(bf_, 1);
        MM_;
    }
#undef BAR
#undef VMC
#undef MM_
#undef RD_B
#undef RD_A
#undef STG_B
#undef STG_A

    if constexpr (MODE == 0) {
        constexpr int N = NTN * BN;
        float* const cbase = Cout + (size_t)(rmA + wm * RPW) * N + tn * BN + wn * 64 + r16;
#pragma unroll
        for (int mi = 0; mi < MI_T; mi++)
#pragma unroll
            for (int r = 0; r < 4; r++) {
                float* dst = cbase + (size_t)(mi * 16 + q16 * 4 + r) * N;
#pragma unroll
                for (int bi = 0; bi < 4; bi++)
                    dst[bi * 16] = acc[mi][bi][r];
            }
    } else {
        const int hb = tn * 2 + (wn >> 1);   // 0..15 q | 16..19 k | 20..23 v (wave-uniform)
        const float sgn = (r16 & 1) ? 1.0f : -1.0f;
#pragma unroll
        for (int mi = 0; mi < MI_T; mi++)
#pragma unroll
            for (int r = 0; r < 4; r++) {
                const int m = rmA + wm * RPW + mi * 16 + q16 * 4 + r;
                const int bb = m >> 11, t = m & 2047;
                if (hb < 20) {  // q or k: RoPE then scatter
                    const float2* tabRow = ropeTab + t * 64;
                    __hip_bfloat16* dst = (hb < 16)
                        ? qo + ((size_t)(bb * NH_ + hb) * T_ + t) * D_
                        : ko + ((size_t)(bb * NKV_ + (hb - 16)) * T_ + t) * D_;
#pragma unroll
                    for (int bi = 0; bi < 4; bi++) {
                        const int dloc = (wn & 1) * 64 + bi * 16 + r16;
                        float v = acc[mi][bi][r];
                        float prt = __shfl_xor(v, 1);
                        float2 cs = tabRow[dloc >> 1];
                        dst[dloc] = __float2bfloat16(fmaf(prt * sgn, cs.y, v * cs.x));
                    }
                } else {        // v: transposed (d, t) store
                    __hip_bfloat16* dst = vT + (size_t)(bb * NKV_ + (hb - 20)) * D_ * T_ + t;
#pragma unroll
                    for (int bi = 0; bi < 4; bi++) {
                        const int dloc = (wn & 1) * 64 + bi * 16 + r16;
                        dst[(size_t)dloc * T_] = __float2bfloat16(acc[mi][bi][r]);
                    }
                }
            }
    }
}

// ---------------- flash attention, GQA-cooperative, split-s flash-decoding ----------------
__global__ __launch_bounds__(256, 3) void attn_kernel(const __hip_bfloat16* __restrict__ Q,
                                                      const __hip_bfloat16* __restrict__ Kt,
                                                      const __hip_bfloat16* __restrict__ Vt,
                                                      __hip_bfloat16* __restrict__ Ao,
                                                      float* __restrict__ O0,
                                                      float* __restrict__ O1,
                                                      float* __restrict__ l0p,
                                                      float* __restrict__ l1p) {
    __shared__ __hip_bfloat16 Ks[2][4096];   // 8 chunks x 512 shorts, x2 buffers
    __shared__ __hip_bfloat16 Vs[2][4096];
    __shared__ __hip_bfloat16 Pl[4][1280];   // per-wave 2 tiles x (16q x 32s, stride 40)

    const int lane = threadIdx.x & 63, wv = threadIdx.x >> 6;
    const int bg = blockIdx.y;                              // 0..7 : (b,g)
    const int u  = (int)blockIdx.x;                         // 0..95 work unit
    int tb, nIt, sIdx;
    if (u < 32)      { tb = u;      nIt = tb + 1;      sIdx = -1; }  // whole row range
    else if (u < 64) { tb = u;      nIt = 32;          sIdx = 0;  }  // s in [0,1024)
    else             { tb = u - 32; nIt = tb + 1 - 32; sIdx = 1;  }  // s in [1024, ...)
    const int sBase = (sIdx == 1) ? 1024 : 0;
    const int b = bg >> 2, g = bg & 3;
    const int h = g * 4 + wv;                               // this wave's q-head
    const int t0 = tb * 32;
    const int q16 = lane >> 4, r16 = lane & 15;

    const __hip_bfloat16* qh = Q + ((size_t)((b * NH_ + h) * T_) + t0) * D_;
    const __hip_bfloat16* kh = Kt + (size_t)(b * NKV_ + g) * T_ * D_;
    const __hip_bfloat16* vh = Vt + (size_t)(b * NKV_ + g) * D_ * T_;

    bf16x8 bqA[4], bqB[4];
#pragma unroll
    for (int kk = 0; kk < 4; kk++) {
        bqA[kk] = *reinterpret_cast<const bf16x8*>(qh + (size_t)r16 * D_ + kk * 32 + q16 * 8);
        bqB[kk] = *reinterpret_cast<const bf16x8*>(qh + (size_t)(16 + r16) * D_ + kk * 32 + q16 * 8);
    }

    float liA = 0.f, liB = 0.f;
    f32x4 oA[8], oB[8];
#pragma unroll
    for (int d = 0; d < 8; d++) {
        oA[d] = (f32x4){0.f, 0.f, 0.f, 0.f};
        oB[d] = (f32x4){0.f, 0.f, 0.f, 0.f};
    }

    const float SCL2 = 0.088388347648318447f * 1.4426950408889634f;  // (1/sqrt(D)) * log2(e)
    const int tqA = t0 + r16;
    const int tqB = t0 + 16 + r16;

    const __hip_bfloat16* gK = kh + (size_t)((wv & 1) * 16 + r16) * D_ + q16 * 8;
    const __hip_bfloat16* gV = vh + (size_t)(((wv - 2) * 4) * 16 + r16) * T_ + q16 * 8;

#define STAGE(bufi, s0_)                                                        \
    do {                                                                        \
        if (wv < 2) {                                                           \
            const __hip_bfloat16* gp = gK + (size_t)(s0_) * D_;                 \
            __hip_bfloat16* lp = &Ks[bufi][(wv * 4) * 512] + lane * 8;          \
            gl_lds16(gp,      lp);                                              \
            gl_lds16(gp + 32, lp + 512);                                        \
            gl_lds16(gp + 64, lp + 1024);                                      \
            gl_lds16(gp + 96, lp + 1536);                                      \
        } else {                                                                \
            const __hip_bfloat16* gp = gV + (s0_);                              \
            __hip_bfloat16* lp = &Vs[bufi][((wv - 2) * 4) * 512] + lane * 8;    \
            gl_lds16(gp,                      lp);                              \
            gl_lds16(gp + (size_t)16 * T_,    lp + 512);                        \
            gl_lds16(gp + (size_t)32 * T_,    lp + 1024);                      \
            gl_lds16(gp + (size_t)48 * T_,    lp + 1536);                      \
        }                                                                       \
    } while (0)

    STAGE(0, sBase);

    for (int j = 0; j < nIt; j++) {
        const int s0 = sBase + j * 32;
        const int cur = j & 1;
        __syncthreads();  // staging of `cur` complete; buffer `cur^1` free
        if (j + 1 < nIt) STAGE(cur ^ 1, s0 + 32);

        f32x4 sc0A = (f32x4){0.f, 0.f, 0.f, 0.f};
        f32x4 sc1A = (f32x4){0.f, 0.f, 0.f, 0.f};
        f32x4 sc0B = (f32x4){0.f, 0.f, 0.f, 0.f};
        f32x4 sc1B = (f32x4){0.f, 0.f, 0.f, 0.f};
        {
            bf16x8 ak[4];
#pragma unroll
            for (int kk = 0; kk < 4; kk++)
                ak[kk] = *reinterpret_cast<const bf16x8*>(&Ks[cur][kk * 512] + lane * 8);
#pragma unroll
            for (int kk = 0; kk < 4; kk++) {
                sc0A = __builtin_amdgcn_mfma_f32_16x16x32_bf16(ak[kk], bqA[kk], sc0A, 0, 0, 0);
                sc0B = __builtin_amdgcn_mfma_f32_16x16x32_bf16(ak[kk], bqB[kk], sc0B, 0, 0, 0);
            }
#pragma unroll
            for (int kk = 0; kk < 4; kk++)
                ak[kk] = *reinterpret_cast<const bf16x8*>(&Ks[cur][(4 + kk) * 512] + lane * 8);
#pragma unroll
            for (int kk = 0; kk < 4; kk++) {
                sc1A = __builtin_amdgcn_mfma_f32_16x16x32_bf16(ak[kk], bqA[kk], sc1A, 0, 0, 0);
                sc1B = __builtin_amdgcn_mfma_f32_16x16x32_bf16(ak[kk], bqB[kk], sc1B, 0, 0, 0);
            }
        }

        ushort4 w0A, w1A, w0B, w1B;
        float psA = 0.f, psB = 0.f;
        if (s0 + 32 > t0) {  // diagonal iteration: causal mask (wave-uniform branch)
#pragma unroll
            for (int r = 0; r < 4; r++) {
                int s_a = s0 + q16 * 4 + r;
                float pa0 = (s_a <= tqA)      ? __builtin_amdgcn_exp2f(sc0A[r] * SCL2) : 0.f;
                float pa1 = (s_a + 16 <= tqA) ? __builtin_amdgcn_exp2f(sc1A[r] * SCL2) : 0.f;
                float pb0 = (s_a <= tqB)      ? __builtin_amdgcn_exp2f(sc0B[r] * SCL2) : 0.f;
                float pb1 = (s_a + 16 <= tqB) ? __builtin_amdgcn_exp2f(sc1B[r] * SCL2) : 0.f;
                psA += pa0 + pa1;
                psB += pb0 + pb1;
                ((unsigned short*)&w0A)[r] = (unsigned short)f2bs(pa0);
                ((unsigned short*)&w1A)[r] = (unsigned short)f2bs(pa1);
                ((unsigned short*)&w0B)[r] = (unsigned short)f2bs(pb0);
                ((unsigned short*)&w1B)[r] = (unsigned short)f2bs(pb1);
            }
        } else {  // interior iteration
#pragma unroll
            for (int r = 0; r < 4; r++) {
                float pa0 = __builtin_amdgcn_exp2f(sc0A[r] * SCL2);
                float pa1 = __builtin_amdgcn_exp2f(sc1A[r] * SCL2);
                float pb0 = __builtin_amdgcn_exp2f(sc0B[r] * SCL2);
                float pb1 = __builtin_amdgcn_exp2f(sc1B[r] * SCL2);
                psA += pa0 + pa1;
                psB += pb0 + pb1;
                ((unsigned short*)&w0A)[r] = (unsigned short)f2bs(pa0);
                ((unsigned short*)&w1A)[r] = (unsigned short)f2bs(pa1);
                ((unsigned short*)&w0B)[r] = (unsigned short)f2bs(pb0);
                ((unsigned short*)&w1B)[r] = (unsigned short)f2bs(pb1);
            }
        }
        liA += psA;
        liB += psB;

        *reinterpret_cast<ushort4*>(&Pl[wv][r16 * 40 + q16 * 4]) = w0A;
        *reinterpret_cast<ushort4*>(&Pl[wv][r16 * 40 + 16 + q16 * 4]) = w1A;
        *reinterpret_cast<ushort4*>(&Pl[wv][640 + r16 * 40 + q16 * 4]) = w0B;
        *reinterpret_cast<ushort4*>(&Pl[wv][640 + r16 * 40 + 16 + q16 * 4]) = w1B;
        asm volatile("s_waitcnt lgkmcnt(0)" ::: "memory");
        bf16x8 pfA = *reinterpret_cast<const bf16x8*>(&Pl[wv][r16 * 40 + q16 * 8]);
        bf16x8 pfB = *reinterpret_cast<const bf16x8*>(&Pl[wv][640 + r16 * 40 + q16 * 8]);

#pragma unroll
        for (int d = 0; d < 8; d++) {
            bf16x8 bv = *reinterpret_cast<const bf16x8*>(&Vs[cur][d * 512] + lane * 8);
            oA[d] = __builtin_amdgcn_mfma_f32_16x16x32_bf16(pfA, bv, oA[d], 0, 0, 0);
            oB[d] = __builtin_amdgcn_mfma_f32_16x16x32_bf16(pfB, bv, oB[d], 0, 0, 0);
        }
    }

    liA += __shfl_xor(liA, 16);
    liA += __shfl_xor(liA, 32);
    liB += __shfl_xor(liB, 16);
    liB += __shfl_xor(liB, 32);

    if (sIdx < 0) {
#pragma unroll
        for (int r = 0; r < 4; r++) {
            float lrA = __shfl(liA, q16 * 4 + r, 16);
            float lrB = __shfl(liB, q16 * 4 + r, 16);
            float invA = 1.0f / lrA;
            float invB = 1.0f / lrB;
            int tA = t0 + q16 * 4 + r;
            __hip_bfloat16* dstA = Ao + (size_t)(b * T_ + tA) * C_ + h * D_ + r16;
            __hip_bfloat16* dstB = dstA + (size_t)16 * C_;
#pragma unroll
            for (int d = 0; d < 8; d++) {
                dstA[d * 16] = __float2bfloat16(oA[d][r] * invA);
                dstB[d * 16] = __float2bfloat16(oB[d][r] * invB);
            }
        }
    } else {
        float* Os = (sIdx == 0) ? O0 : O1;
        float* ls = (sIdx == 0) ? l0p : l1p;
        const size_t rb = (size_t)(b * NH_ + h) * 1024 + (size_t)(t0 - 1024);
        if (q16 == 0) {
            ls[rb + r16]      = liA;
            ls[rb + 16 + r16] = liB;
        }
#pragma unroll
        for (int r = 0; r < 4; r++) {
            int rowl = q16 * 4 + r;
            float* dA = Os + (rb + rowl) * 128 + r16;
            float* dB = Os + (rb + 16 + rowl) * 128 + r16;
#pragma unroll
            for (int d = 0; d < 8; d++) {
                dA[d * 16] = oA[d][r];
                dB[d * 16] = oB[d][r];
            }
        }
    }
#undef STAGE
}

// ---------------- combine split-s partials (rows t >= 1024) ----------------
__global__ void attn_combine(const float* __restrict__ O0, const float* __restrict__ O1,
                             const float* __restrict__ l0, const float* __restrict__ l1,
                             __hip_bfloat16* __restrict__ Ao) {
    int idx = blockIdx.x * blockDim.x + threadIdx.x;   // [0, 32768*32)
    int row = idx >> 5, d4 = (idx & 31) << 2;
    int bh = row >> 10, tl = row & 1023;
    int b = bh >> 4, h = bh & 15;
    float inv = 1.0f / (l0[row] + l1[row]);
    float4 a = *reinterpret_cast<const float4*>(O0 + (size_t)row * 128 + d4);
    float4 c = *reinterpret_cast<const float4*>(O1 + (size_t)row * 128 + d4);
    short4 o;
    o.x = f2bs((a.x + c.x) * inv);
    o.y = f2bs((a.y + c.y) * inv);
    o.z = f2bs((a.z + c.z) * inv);
    o.w = f2bs((a.w + c.w) * inv);
    *reinterpret_cast<short4*>(Ao + (size_t)(b * T_ + 1024 + tl) * C_ + h * D_ + d4) = o;
}

// ---------------- launch ----------------
extern "C" void kernel_launch(void* const* d_in, const int* in_sizes, int n_in,
                              void* d_out, int out_size, void* d_ws, size_t ws_size,
                              hipStream_t stream) {
    const float* x  = (const float*)d_in[0];
    const float* Wq = (const float*)d_in[1];
    const float* Wk = (const float*)d_in[2];
    const float* Wv = (const float*)d_in[3];
    const float* Wo = (const float*)d_in[4];
    float* out = (float*)d_out;
    char* ws = (char*)d_ws;

    __hip_bfloat16* xb   = (__hip_bfloat16*)(ws + 0);          // 16.78 MB (dead after GEMM1)
    __hip_bfloat16* wcat = (__hip_bfloat16*)(ws + 16777216);   // 12.58 MB
    float2*         ropeTab = (float2*)(ws + 29360128);        // 1.05 MB
    __hip_bfloat16* wob  = (__hip_bfloat16*)(ws + 30408704);   // 8.39 MB (live until GEMM2)
    __hip_bfloat16* qatt = (__hip_bfloat16*)(ws + 38797312);   // 16.78 MB
    __hip_bfloat16* katt = (__hip_bfloat16*)(ws + 55574528);   // 4.19 MB
    __hip_bfloat16* vT   = (__hip_bfloat16*)(ws + 59768832);   // 4.19 MB
    __hip_bfloat16* aout = (__hip_bfloat16*)(ws + 63963136);   // 16.78 MB
    float* O0 = (float*)(ws + 0);                              // overlays dead xb
    float* O1 = (float*)(ws + 80740352);                       // 16.78 MB
    float* l0 = (float*)(ws + 97517568);                       // 128 KB
    float* l1 = (float*)(ws + 97648640);                       // 128 KB (end ~97.8 MB)

    static bool s_attr_done = false;
    if (!s_attr_done) {
        hipFuncSetAttribute(reinterpret_cast<const void*>(&gemm_ff<1, 256, 12>),
                            hipFuncAttributeMaxDynamicSharedMemorySize, 131072);
        hipFuncSetAttribute(reinterpret_cast<const void*>(&gemm_ff<0, 128, 16>),
                            hipFuncAttributeMaxDynamicSharedMemorySize, 98304);
        s_attr_done = true;
    }

    const int thr = 256;
    prep_kernel<<<18944, thr, 0, stream>>>(x, Wq, Wk, Wv, Wo, xb, wcat, wob, ropeTab);

    // QKV projection + RoPE + scatter: M=4096, N=3072 (BN=256 -> 12 tn), grid 192
    gemm_ff<1, 256, 12><<<192, 512, 131072, stream>>>(xb, wcat, ropeTab, qatt, katt, vT, nullptr);

    attn_kernel<<<dim3(96, 8), 256, 0, stream>>>(qatt, katt, vT, aout, O0, O1, l0, l1);
    attn_combine<<<(2 * NH_ * 1024 * 32) / thr, thr, 0, stream>>>(O0, O1, l0, l1, aout);

    // Output projection: M=4096, N=2048 (BN=128 -> 16 tn), grid 256 = 100% CU util
    gemm_ff<0, 128, 16><<<256, 512, 98304, stream>>>(aout, wob, nullptr, nullptr, nullptr, nullptr, out);
}

// Round 6
// 282.912 us; speedup vs baseline: 1.0833x; 1.0358x over previous
//
#include <hip/hip_runtime.h>
#include <hip/hip_bf16.h>
#include <stdint.h>

#define B_   2
#define T_   2048
#define C_   2048
#define NH_  16
#define NKV_ 4
#define D_   128
#define NREP_ 4

typedef __attribute__((ext_vector_type(8))) short bf16x8;
typedef __attribute__((ext_vector_type(4))) float f32x4;

__device__ inline short f2bs(float f) {
    __hip_bfloat16 h = __float2bfloat16(f);
    return *reinterpret_cast<short*>(&h);
}

__device__ inline void gl_lds16(const __hip_bfloat16* g, __hip_bfloat16* l) {
    __builtin_amdgcn_global_load_lds(
        (const __attribute__((address_space(1))) unsigned int*)g,
        (__attribute__((address_space(3))) unsigned int*)l,
        16, 0, 0);
}

// ---------------- merged prep: all f32->bf16 converts + RoPE cos/sin table ----------------
__global__ void prep_kernel(const float* __restrict__ x,  const float* __restrict__ Wq,
                            const float* __restrict__ Wk, const float* __restrict__ Wv,
                            const float* __restrict__ Wo,
                            __hip_bfloat16* __restrict__ xb, __hip_bfloat16* __restrict__ wcat,
                            __hip_bfloat16* __restrict__ wob, float2* __restrict__ ropeTab) {
    int tid = blockIdx.x * blockDim.x + threadIdx.x;
    const int CVT_THREADS = 4718592;
    if (tid < CVT_THREADS) {
        int i4 = tid * 4;
        const float* src;
        __hip_bfloat16* dst;
        int off;
        if (i4 < 8388608)       { src = x;  dst = xb;             off = i4; }
        else if (i4 < 12582912) { src = Wq; dst = wcat;           off = i4 - 8388608; }
        else if (i4 < 13631488) { src = Wk; dst = wcat + 4194304; off = i4 - 12582912; }
        else if (i4 < 14680064) { src = Wv; dst = wcat + 5242880; off = i4 - 13631488; }
        else                    { src = Wo; dst = wob;            off = i4 - 14680064; }
        float4 v = *reinterpret_cast<const float4*>(src + off);
        short4 o;
        o.x = f2bs(v.x); o.y = f2bs(v.y); o.z = f2bs(v.z); o.w = f2bs(v.w);
        *reinterpret_cast<short4*>(dst + off) = o;
    } else {
        int e = tid - CVT_THREADS;
        if (e < 131072) {
            int t = e >> 6, p = e & 63;
            float inv = __expf(-(float)p * (9.210340371976184f / 64.0f));  // 10000^(-p/64)
            float ang = (float)t * inv;
            ropeTab[e] = make_float2(cosf(ang), sinf(ang));
        }
    }
}

// ---------------- GEMM1 (m97 structure) with fused RoPE + q/k/v scatter epilogue ----------------
// PROVEN 78.0 us in R3 on this harness. y = x @ Wcat^T (M=4096, N=3072, K=2048).
// Column segments q[0,2048) k[2048,2560) v[2560,3072) are 128-aligned, so each
// 128-col block (blockIdx.x = hb) is entirely one head of one segment. RoPE pairs
// (2p, 2p+1) sit in adjacent lanes: one __shfl_xor(v,1) gives the partner; cos/sin
// from the precomputed L2-resident ropeTab.
// R4/R5 lesson: 256-tile deep-pipeline rewrites (1 block/CU, barrier-lockstep)
// landed at 86-88 us — the m97 3-blocks/CU implicit overlap wins at this shape.
__global__ __launch_bounds__(256) void gemm_qkv(const __hip_bfloat16* __restrict__ A,
                                                const __hip_bfloat16* __restrict__ Bm,
                                                const float2* __restrict__ ropeTab,
                                                __hip_bfloat16* __restrict__ qo,
                                                __hip_bfloat16* __restrict__ ko,
                                                __hip_bfloat16* __restrict__ vT) {
    const int K = 2048;
    __shared__ __hip_bfloat16 As[128 * 32];
    __shared__ __hip_bfloat16 Bs[128 * 32];
    const int tid  = threadIdx.x;
    const int lane = tid & 63;
    const int wv   = tid >> 6;
    const int m0 = blockIdx.y * 128, n0 = blockIdx.x * 128;
    const int wm = (wv >> 1) * 64, wn = (wv & 1) * 64;
    const int q16 = lane >> 4, r16 = lane & 15;

    f32x4 acc[4][4] = {};

    const int lrow = tid >> 2;
    const int lcol = (tid & 3) * 8;
    const __hip_bfloat16* aG = A  + (size_t)(m0 + lrow) * K + lcol;
    const __hip_bfloat16* bG = Bm + (size_t)(n0 + lrow) * K + lcol;
    __hip_bfloat16* aL = As + tid * 8;
    __hip_bfloat16* bL = Bs + tid * 8;

    for (int k0 = 0; k0 < K; k0 += 32) {
        __syncthreads();
        gl_lds16(aG + k0,          aL);
        gl_lds16(aG + 64 * K + k0, aL + 2048);
        gl_lds16(bG + k0,          bL);
        gl_lds16(bG + 64 * K + k0, bL + 2048);
        __syncthreads();
        bf16x8 af[4], bfr[4];
#pragma unroll
        for (int i = 0; i < 4; i++)
            af[i] = *reinterpret_cast<const bf16x8*>(As + (wm + i * 16 + r16) * 32 + q16 * 8);
#pragma unroll
        for (int j = 0; j < 4; j++)
            bfr[j] = *reinterpret_cast<const bf16x8*>(Bs + (wn + j * 16 + r16) * 32 + q16 * 8);
#pragma unroll
        for (int i = 0; i < 4; i++)
#pragma unroll
            for (int j = 0; j < 4; j++)
                acc[i][j] = __builtin_amdgcn_mfma_f32_16x16x32_bf16(af[i], bfr[j], acc[i][j], 0, 0, 0);
    }

    const int hb = n0 >> 7;   // 0..15 q-head | 16..19 k-head | 20..23 v-head (block-uniform)
    const float sgn = (r16 & 1) ? 1.0f : -1.0f;
#pragma unroll
    for (int i = 0; i < 4; i++)
#pragma unroll
        for (int r = 0; r < 4; r++) {
            const int m = m0 + wm + i * 16 + q16 * 4 + r;
            const int b = m >> 11, t = m & 2047;
            if (hb < 20) {  // q or k: RoPE then scatter
                const float2* tabRow = ropeTab + t * 64;
                __hip_bfloat16* dst = (hb < 16)
                    ? qo + ((size_t)(b * NH_ + hb) * T_ + t) * D_
                    : ko + ((size_t)(b * NKV_ + (hb - 16)) * T_ + t) * D_;
#pragma unroll
                for (int j = 0; j < 4; j++) {
                    const int dloc = wn + j * 16 + r16;
                    float v = acc[i][j][r];
                    float prt = __shfl_xor(v, 1);
                    float2 cs = tabRow[dloc >> 1];
                    // even lane: re = v*c - prt*s ; odd lane: ro = v*c + prt*s
                    float res = fmaf(prt * sgn, cs.y, v * cs.x);
                    dst[dloc] = __float2bfloat16(res);
                }
            } else {        // v: no rope, transposed (d, t) store
                __hip_bfloat16* dst = vT + (size_t)(b * NKV_ + (hb - 20)) * D_ * T_ + t;
#pragma unroll
                for (int j = 0; j < 4; j++) {
                    const int d = wn + j * 16 + r16;
                    dst[(size_t)d * T_] = __float2bfloat16(acc[i][j][r]);
                }
            }
        }
}

// ---------------- 256xBNxK64 free-flow bf16 GEMM, C = A @ B^T (R5, kept for GEMM2) ----------------
// dbuf LDS + counted vmcnt + 2 phases per K-step, K-slice-half staging.
// Measured (R5 totals): ~19 us faster than the m97 gemm_bt<float> at GEMM2's shape.
template <int MODE, int BN, int NTN>
__global__ __launch_bounds__(512, 2) void gemm_ff(
    const __hip_bfloat16* __restrict__ A,
    const __hip_bfloat16* __restrict__ Bm,
    const float2* __restrict__ ropeTab,
    __hip_bfloat16* __restrict__ qo,
    __hip_bfloat16* __restrict__ ko,
    __hip_bfloat16* __restrict__ vT,
    float* __restrict__ Cout) {
    constexpr int K = 2048;
    constexpr int NT = K / 64;           // 32 K-steps
    constexpr int WN = BN / 64;          // waves along N
    constexpr int WM = 8 / WN;           // waves along M
    constexpr int RPW = 256 / WM;        // rows per wave
    constexpr int MI_T = RPW / 16;
    constexpr int BSZ = BN * 64;         // B slice bytes
    constexpr int BLOADS = BSZ / 8192;
    extern __shared__ char lds[];        // A: [buf][slice]16KB at 0; B at 65536

    const int tid = threadIdx.x;
    const int lane = tid & 63;
    const int wid = tid >> 6;
    const int wm = wid / WN, wn = wid % WN;
    const int q16 = lane >> 4, r16 = lane & 15;

    const int cpx = (int)gridDim.x >> 3;
    const int bs = ((int)blockIdx.x & 7) * cpx + ((int)blockIdx.x >> 3);
    const int tm = bs / NTN, tn = bs % NTN;
    const int rmA = tm * 256, rmB = tn * BN;

    const int csw = (q16 << 4) ^ ((r16 & 3) << 4);

    f32x4 acc[MI_T][4] = {};
    bf16x8 aF[MI_T], bF[4];

#define STG_A(buf_, sl_, kstep_)                                                     \
    { _Pragma("unroll") for (int li = 0; li < 2; li++) {                             \
        const int L_ = li * 8192 + tid * 16;                                         \
        const int rw_ = L_ >> 6;                                                     \
        const int cb_ = (L_ & 63) ^ ((rw_ & 3) << 4);                                \
        gl_lds16(A + (size_t)(rmA + rw_) * K + (kstep_) * 64 + (sl_) * 32 + (cb_ >> 1), \
                 (__hip_bfloat16*)(lds + (buf_) * 32768 + (sl_) * 16384 + L_));      \
    } }
#define STG_B(buf_, sl_, kstep_)                                                     \
    { _Pragma("unroll") for (int li = 0; li < BLOADS; li++) {                        \
        const int L_ = li * 8192 + tid * 16;                                         \
        const int rw_ = L_ >> 6;                                                     \
        const int cb_ = (L_ & 63) ^ ((rw_ & 3) << 4);                                \
        gl_lds16(Bm + (size_t)(rmB + rw_) * K + (kstep_) * 64 + (sl_) * 32 + (cb_ >> 1), \
                 (__hip_bfloat16*)(lds + 65536 + (buf_) * 2 * BSZ + (sl_) * BSZ + L_)); \
    } }
#define RD_A(buf_, sl_)                                                              \
    { _Pragma("unroll") for (int mi = 0; mi < MI_T; mi++)                            \
        aF[mi] = *(const bf16x8*)(lds + (buf_) * 32768 + (sl_) * 16384 +             \
                                  (wm * RPW + mi * 16 + r16) * 64 + csw); }
#define RD_B(buf_, sl_)                                                              \
    { _Pragma("unroll") for (int bi = 0; bi < 4; bi++)                               \
        bF[bi] = *(const bf16x8*)(lds + 65536 + (buf_) * 2 * BSZ + (sl_) * BSZ +     \
                                  (wn * 64 + bi * 16 + r16) * 64 + csw); }
#define MM_                                                                          \
    { __builtin_amdgcn_s_setprio(1);                                                 \
      _Pragma("unroll") for (int mi = 0; mi < MI_T; mi++)                            \
      _Pragma("unroll") for (int bi = 0; bi < 4; bi++)                               \
          acc[mi][bi] = __builtin_amdgcn_mfma_f32_16x16x32_bf16(                     \
              aF[mi], bF[bi], acc[mi][bi], 0, 0, 0);                                 \
      __builtin_amdgcn_s_setprio(0); }
#define VMC                                                                          \
    { if constexpr (BLOADS == 2) { asm volatile("s_waitcnt vmcnt(4)" ::: "memory"); } \
      else                       { asm volatile("s_waitcnt vmcnt(3)" ::: "memory"); } }
#define BAR __builtin_amdgcn_s_barrier()

    STG_A(0, 0, 0); STG_B(0, 0, 0);
    STG_A(0, 1, 0); STG_B(0, 1, 0);
    VMC; BAR;

    for (int u = 0; u < NT - 1; u++) {
        const int bf_ = u & 1;
        RD_A(bf_, 0); RD_B(bf_, 0);
        STG_A(bf_ ^ 1, 0, u + 1); STG_B(bf_ ^ 1, 0, u + 1);
        MM_;
        VMC; BAR;
        RD_A(bf_, 1); RD_B(bf_, 1);
        STG_A(bf_ ^ 1, 1, u + 1); STG_B(bf_ ^ 1, 1, u + 1);
        MM_;
        VMC; BAR;
    }
    {
        const int bf_ = (NT - 1) & 1;
        RD_A(bf_, 0); RD_B(bf_, 0);
        MM_;
        asm volatile("s_waitcnt vmcnt(0)" ::: "memory"); BAR;
        RD_A(bf_, 1); RD_B(bf_, 1);
        MM_;
    }
#undef BAR
#undef VMC
#undef MM_
#undef RD_B
#undef RD_A
#undef STG_B
#undef STG_A

    if constexpr (MODE == 0) {
        constexpr int N = NTN * BN;
        float* const cbase = Cout + (size_t)(rmA + wm * RPW) * N + tn * BN + wn * 64 + r16;
#pragma unroll
        for (int mi = 0; mi < MI_T; mi++)
#pragma unroll
            for (int r = 0; r < 4; r++) {
                float* dst = cbase + (size_t)(mi * 16 + q16 * 4 + r) * N;
#pragma unroll
                for (int bi = 0; bi < 4; bi++)
                    dst[bi * 16] = acc[mi][bi][r];
            }
    } else {
        const int hb = tn * 2 + (wn >> 1);
        const float sgn = (r16 & 1) ? 1.0f : -1.0f;
#pragma unroll
        for (int mi = 0; mi < MI_T; mi++)
#pragma unroll
            for (int r = 0; r < 4; r++) {
                const int m = rmA + wm * RPW + mi * 16 + q16 * 4 + r;
                const int bb = m >> 11, t = m & 2047;
                if (hb < 20) {
                    const float2* tabRow = ropeTab + t * 64;
                    __hip_bfloat16* dst = (hb < 16)
                        ? qo + ((size_t)(bb * NH_ + hb) * T_ + t) * D_
                        : ko + ((size_t)(bb * NKV_ + (hb - 16)) * T_ + t) * D_;
#pragma unroll
                    for (int bi = 0; bi < 4; bi++) {
                        const int dloc = (wn & 1) * 64 + bi * 16 + r16;
                        float v = acc[mi][bi][r];
                        float prt = __shfl_xor(v, 1);
                        float2 cs = tabRow[dloc >> 1];
                        dst[dloc] = __float2bfloat16(fmaf(prt * sgn, cs.y, v * cs.x));
                    }
                } else {
                    __hip_bfloat16* dst = vT + (size_t)(bb * NKV_ + (hb - 20)) * D_ * T_ + t;
#pragma unroll
                    for (int bi = 0; bi < 4; bi++) {
                        const int dloc = (wn & 1) * 64 + bi * 16 + r16;
                        dst[(size_t)dloc * T_] = __float2bfloat16(acc[mi][bi][r]);
                    }
                }
            }
    }
}

// ---------------- flash attention, GQA-cooperative, split-s flash-decoding ----------------
__global__ __launch_bounds__(256, 3) void attn_kernel(const __hip_bfloat16* __restrict__ Q,
                                                      const __hip_bfloat16* __restrict__ Kt,
                                                      const __hip_bfloat16* __restrict__ Vt,
                                                      __hip_bfloat16* __restrict__ Ao,
                                                      float* __restrict__ O0,
                                                      float* __restrict__ O1,
                                                      float* __restrict__ l0p,
                                                      float* __restrict__ l1p) {
    __shared__ __hip_bfloat16 Ks[2][4096];   // 8 chunks x 512 shorts, x2 buffers
    __shared__ __hip_bfloat16 Vs[2][4096];
    __shared__ __hip_bfloat16 Pl[4][1280];   // per-wave 2 tiles x (16q x 32s, stride 40)

    const int lane = threadIdx.x & 63, wv = threadIdx.x >> 6;
    const int bg = blockIdx.y;                              // 0..7 : (b,g)
    const int u  = (int)blockIdx.x;                         // 0..95 work unit
    int tb, nIt, sIdx;
    if (u < 32)      { tb = u;      nIt = tb + 1;      sIdx = -1; }  // whole row range
    else if (u < 64) { tb = u;      nIt = 32;          sIdx = 0;  }  // s in [0,1024)
    else             { tb = u - 32; nIt = tb + 1 - 32; sIdx = 1;  }  // s in [1024, ...)
    const int sBase = (sIdx == 1) ? 1024 : 0;
    const int b = bg >> 2, g = bg & 3;
    const int h = g * 4 + wv;                               // this wave's q-head
    const int t0 = tb * 32;
    const int q16 = lane >> 4, r16 = lane & 15;

    const __hip_bfloat16* qh = Q + ((size_t)((b * NH_ + h) * T_) + t0) * D_;
    const __hip_bfloat16* kh = Kt + (size_t)(b * NKV_ + g) * T_ * D_;
    const __hip_bfloat16* vh = Vt + (size_t)(b * NKV_ + g) * D_ * T_;

    bf16x8 bqA[4], bqB[4];
#pragma unroll
    for (int kk = 0; kk < 4; kk++) {
        bqA[kk] = *reinterpret_cast<const bf16x8*>(qh + (size_t)r16 * D_ + kk * 32 + q16 * 8);
        bqB[kk] = *reinterpret_cast<const bf16x8*>(qh + (size_t)(16 + r16) * D_ + kk * 32 + q16 * 8);
    }

    float liA = 0.f, liB = 0.f;
    f32x4 oA[8], oB[8];
#pragma unroll
    for (int d = 0; d < 8; d++) {
        oA[d] = (f32x4){0.f, 0.f, 0.f, 0.f};
        oB[d] = (f32x4){0.f, 0.f, 0.f, 0.f};
    }

    const float SCL2 = 0.088388347648318447f * 1.4426950408889634f;  // (1/sqrt(D)) * log2(e)
    const int tqA = t0 + r16;
    const int tqB = t0 + 16 + r16;

    const __hip_bfloat16* gK = kh + (size_t)((wv & 1) * 16 + r16) * D_ + q16 * 8;
    const __hip_bfloat16* gV = vh + (size_t)(((wv - 2) * 4) * 16 + r16) * T_ + q16 * 8;

#define STAGE(bufi, s0_)                                                        \
    do {                                                                        \
        if (wv < 2) {                                                           \
            const __hip_bfloat16* gp = gK + (size_t)(s0_) * D_;                 \
            __hip_bfloat16* lp = &Ks[bufi][(wv * 4) * 512] + lane * 8;          \
            gl_lds16(gp,      lp);                                              \
            gl_lds16(gp + 32, lp + 512);                                        \
            gl_lds16(gp + 64, lp + 1024);                                      \
            gl_lds16(gp + 96, lp + 1536);                                      \
        } else {                                                                \
            const __hip_bfloat16* gp = gV + (s0_);                              \
            __hip_bfloat16* lp = &Vs[bufi][((wv - 2) * 4) * 512] + lane * 8;    \
            gl_lds16(gp,                      lp);                              \
            gl_lds16(gp + (size_t)16 * T_,    lp + 512);                        \
            gl_lds16(gp + (size_t)32 * T_,    lp + 1024);                      \
            gl_lds16(gp + (size_t)48 * T_,    lp + 1536);                      \
        }                                                                       \
    } while (0)

    STAGE(0, sBase);

    for (int j = 0; j < nIt; j++) {
        const int s0 = sBase + j * 32;
        const int cur = j & 1;
        __syncthreads();  // staging of `cur` complete; buffer `cur^1` free
        if (j + 1 < nIt) STAGE(cur ^ 1, s0 + 32);

        f32x4 sc0A = (f32x4){0.f, 0.f, 0.f, 0.f};
        f32x4 sc1A = (f32x4){0.f, 0.f, 0.f, 0.f};
        f32x4 sc0B = (f32x4){0.f, 0.f, 0.f, 0.f};
        f32x4 sc1B = (f32x4){0.f, 0.f, 0.f, 0.f};
        {
            bf16x8 ak[4];
#pragma unroll
            for (int kk = 0; kk < 4; kk++)
                ak[kk] = *reinterpret_cast<const bf16x8*>(&Ks[cur][kk * 512] + lane * 8);
#pragma unroll
            for (int kk = 0; kk < 4; kk++) {
                sc0A = __builtin_amdgcn_mfma_f32_16x16x32_bf16(ak[kk], bqA[kk], sc0A, 0, 0, 0);
                sc0B = __builtin_amdgcn_mfma_f32_16x16x32_bf16(ak[kk], bqB[kk], sc0B, 0, 0, 0);
            }
#pragma unroll
            for (int kk = 0; kk < 4; kk++)
                ak[kk] = *reinterpret_cast<const bf16x8*>(&Ks[cur][(4 + kk) * 512] + lane * 8);
#pragma unroll
            for (int kk = 0; kk < 4; kk++) {
                sc1A = __builtin_amdgcn_mfma_f32_16x16x32_bf16(ak[kk], bqA[kk], sc1A, 0, 0, 0);
                sc1B = __builtin_amdgcn_mfma_f32_16x16x32_bf16(ak[kk], bqB[kk], sc1B, 0, 0, 0);
            }
        }

        ushort4 w0A, w1A, w0B, w1B;
        float psA = 0.f, psB = 0.f;
        if (s0 + 32 > t0) {  // diagonal iteration: causal mask (wave-uniform branch)
#pragma unroll
            for (int r = 0; r < 4; r++) {
                int s_a = s0 + q16 * 4 + r;
                float pa0 = (s_a <= tqA)      ? __builtin_amdgcn_exp2f(sc0A[r] * SCL2) : 0.f;
                float pa1 = (s_a + 16 <= tqA) ? __builtin_amdgcn_exp2f(sc1A[r] * SCL2) : 0.f;
                float pb0 = (s_a <= tqB)      ? __builtin_amdgcn_exp2f(sc0B[r] * SCL2) : 0.f;
                float pb1 = (s_a + 16 <= tqB) ? __builtin_amdgcn_exp2f(sc1B[r] * SCL2) : 0.f;
                psA += pa0 + pa1;
                psB += pb0 + pb1;
                ((unsigned short*)&w0A)[r] = (unsigned short)f2bs(pa0);
                ((unsigned short*)&w1A)[r] = (unsigned short)f2bs(pa1);
                ((unsigned short*)&w0B)[r] = (unsigned short)f2bs(pb0);
                ((unsigned short*)&w1B)[r] = (unsigned short)f2bs(pb1);
            }
        } else {  // interior iteration
#pragma unroll
            for (int r = 0; r < 4; r++) {
                float pa0 = __builtin_amdgcn_exp2f(sc0A[r] * SCL2);
                float pa1 = __builtin_amdgcn_exp2f(sc1A[r] * SCL2);
                float pb0 = __builtin_amdgcn_exp2f(sc0B[r] * SCL2);
                float pb1 = __builtin_amdgcn_exp2f(sc1B[r] * SCL2);
                psA += pa0 + pa1;
                psB += pb0 + pb1;
                ((unsigned short*)&w0A)[r] = (unsigned short)f2bs(pa0);
                ((unsigned short*)&w1A)[r] = (unsigned short)f2bs(pa1);
                ((unsigned short*)&w0B)[r] = (unsigned short)f2bs(pb0);
                ((unsigned short*)&w1B)[r] = (unsigned short)f2bs(pb1);
            }
        }
        liA += psA;
        liB += psB;

        *reinterpret_cast<ushort4*>(&Pl[wv][r16 * 40 + q16 * 4]) = w0A;
        *reinterpret_cast<ushort4*>(&Pl[wv][r16 * 40 + 16 + q16 * 4]) = w1A;
        *reinterpret_cast<ushort4*>(&Pl[wv][640 + r16 * 40 + q16 * 4]) = w0B;
        *reinterpret_cast<ushort4*>(&Pl[wv][640 + r16 * 40 + 16 + q16 * 4]) = w1B;
        asm volatile("s_waitcnt lgkmcnt(0)" ::: "memory");
        bf16x8 pfA = *reinterpret_cast<const bf16x8*>(&Pl[wv][r16 * 40 + q16 * 8]);
        bf16x8 pfB = *reinterpret_cast<const bf16x8*>(&Pl[wv][640 + r16 * 40 + q16 * 8]);

#pragma unroll
        for (int d = 0; d < 8; d++) {
            bf16x8 bv = *reinterpret_cast<const bf16x8*>(&Vs[cur][d * 512] + lane * 8);
            oA[d] = __builtin_amdgcn_mfma_f32_16x16x32_bf16(pfA, bv, oA[d], 0, 0, 0);
            oB[d] = __builtin_amdgcn_mfma_f32_16x16x32_bf16(pfB, bv, oB[d], 0, 0, 0);
        }
    }

    liA += __shfl_xor(liA, 16);
    liA += __shfl_xor(liA, 32);
    liB += __shfl_xor(liB, 16);
    liB += __shfl_xor(liB, 32);

    if (sIdx < 0) {
#pragma unroll
        for (int r = 0; r < 4; r++) {
            float lrA = __shfl(liA, q16 * 4 + r, 16);
            float lrB = __shfl(liB, q16 * 4 + r, 16);
            float invA = 1.0f / lrA;
            float invB = 1.0f / lrB;
            int tA = t0 + q16 * 4 + r;
            __hip_bfloat16* dstA = Ao + (size_t)(b * T_ + tA) * C_ + h * D_ + r16;
            __hip_bfloat16* dstB = dstA + (size_t)16 * C_;
#pragma unroll
            for (int d = 0; d < 8; d++) {
                dstA[d * 16] = __float2bfloat16(oA[d][r] * invA);
                dstB[d * 16] = __float2bfloat16(oB[d][r] * invB);
            }
        }
    } else {
        float* Os = (sIdx == 0) ? O0 : O1;
        float* ls = (sIdx == 0) ? l0p : l1p;
        const size_t rb = (size_t)(b * NH_ + h) * 1024 + (size_t)(t0 - 1024);
        if (q16 == 0) {
            ls[rb + r16]      = liA;
            ls[rb + 16 + r16] = liB;
        }
#pragma unroll
        for (int r = 0; r < 4; r++) {
            int rowl = q16 * 4 + r;
            float* dA = Os + (rb + rowl) * 128 + r16;
            float* dB = Os + (rb + 16 + rowl) * 128 + r16;
#pragma unroll
            for (int d = 0; d < 8; d++) {
                dA[d * 16] = oA[d][r];
                dB[d * 16] = oB[d][r];
            }
        }
    }
#undef STAGE
}

// ---------------- combine split-s partials (rows t >= 1024) ----------------
__global__ void attn_combine(const float* __restrict__ O0, const float* __restrict__ O1,
                             const float* __restrict__ l0, const float* __restrict__ l1,
                             __hip_bfloat16* __restrict__ Ao) {
    int idx = blockIdx.x * blockDim.x + threadIdx.x;   // [0, 32768*32)
    int row = idx >> 5, d4 = (idx & 31) << 2;
    int bh = row >> 10, tl = row & 1023;
    int b = bh >> 4, h = bh & 15;
    float inv = 1.0f / (l0[row] + l1[row]);
    float4 a = *reinterpret_cast<const float4*>(O0 + (size_t)row * 128 + d4);
    float4 c = *reinterpret_cast<const float4*>(O1 + (size_t)row * 128 + d4);
    short4 o;
    o.x = f2bs((a.x + c.x) * inv);
    o.y = f2bs((a.y + c.y) * inv);
    o.z = f2bs((a.z + c.z) * inv);
    o.w = f2bs((a.w + c.w) * inv);
    *reinterpret_cast<short4*>(Ao + (size_t)(b * T_ + 1024 + tl) * C_ + h * D_ + d4) = o;
}

// ---------------- launch ----------------
extern "C" void kernel_launch(void* const* d_in, const int* in_sizes, int n_in,
                              void* d_out, int out_size, void* d_ws, size_t ws_size,
                              hipStream_t stream) {
    const float* x  = (const float*)d_in[0];
    const float* Wq = (const float*)d_in[1];
    const float* Wk = (const float*)d_in[2];
    const float* Wv = (const float*)d_in[3];
    const float* Wo = (const float*)d_in[4];
    float* out = (float*)d_out;
    char* ws = (char*)d_ws;

    __hip_bfloat16* xb   = (__hip_bfloat16*)(ws + 0);          // 16.78 MB (dead after GEMM1)
    __hip_bfloat16* wcat = (__hip_bfloat16*)(ws + 16777216);   // 12.58 MB
    float2*         ropeTab = (float2*)(ws + 29360128);        // 1.05 MB
    __hip_bfloat16* wob  = (__hip_bfloat16*)(ws + 30408704);   // 8.39 MB (live until GEMM2)
    __hip_bfloat16* qatt = (__hip_bfloat16*)(ws + 38797312);   // 16.78 MB
    __hip_bfloat16* katt = (__hip_bfloat16*)(ws + 55574528);   // 4.19 MB
    __hip_bfloat16* vT   = (__hip_bfloat16*)(ws + 59768832);   // 4.19 MB
    __hip_bfloat16* aout = (__hip_bfloat16*)(ws + 63963136);   // 16.78 MB
    float* O0 = (float*)(ws + 0);                              // overlays dead xb
    float* O1 = (float*)(ws + 80740352);                       // 16.78 MB
    float* l0 = (float*)(ws + 97517568);                       // 128 KB
    float* l1 = (float*)(ws + 97648640);                       // 128 KB (end ~97.8 MB)

    static bool s_attr_done = false;
    if (!s_attr_done) {
        hipFuncSetAttribute(reinterpret_cast<const void*>(&gemm_ff<0, 128, 16>),
                            hipFuncAttributeMaxDynamicSharedMemorySize, 98304);
        s_attr_done = true;
    }

    const int thr = 256;
    prep_kernel<<<18944, thr, 0, stream>>>(x, Wq, Wk, Wv, Wo, xb, wcat, wob, ropeTab);

    // QKV projection + RoPE + scatter: m97 structure, grid 24x32 = 768 blocks, 3/CU
    gemm_qkv<<<dim3(24, 32), 256, 0, stream>>>(xb, wcat, ropeTab, qatt, katt, vT);

    attn_kernel<<<dim3(96, 8), 256, 0, stream>>>(qatt, katt, vT, aout, O0, O1, l0, l1);
    attn_combine<<<(2 * NH_ * 1024 * 32) / thr, thr, 0, stream>>>(O0, O1, l0, l1, aout);

    // Output projection: M=4096, N=2048 (BN=128 -> 16 tn), grid 256
    gemm_ff<0, 128, 16><<<256, 512, 98304, stream>>>(aout, wob, nullptr, nullptr, nullptr, nullptr, out);
}

// Round 9
// 281.681 us; speedup vs baseline: 1.0880x; 1.0044x over previous
//
#include <hip/hip_runtime.h>
#include <hip/hip_bf16.h>
#include <stdint.h>

#define B_   2
#define T_   2048
#define C_   2048
#define NH_  16
#define NKV_ 4
#define D_   128
#define NREP_ 4

typedef __attribute__((ext_vector_type(8))) short bf16x8;
typedef __attribute__((ext_vector_type(4))) short bf16x4;
typedef __attribute__((ext_vector_type(4))) float f32x4;

// PV-in-place path: 16x16x16 bf16 MFMA (K=16). Score C-layout == its A-layout.
#if __has_builtin(__builtin_amdgcn_mfma_f32_16x16x16bf16_1k)
#define HAVE_MFMA16 1
#define MFMA16(a, b, c) __builtin_amdgcn_mfma_f32_16x16x16bf16_1k(a, b, c, 0, 0, 0)
#else
#define HAVE_MFMA16 0
#endif

__device__ inline short f2bs(float f) {
    __hip_bfloat16 h = __float2bfloat16(f);
    return *reinterpret_cast<short*>(&h);
}

__device__ inline void gl_lds16(const __hip_bfloat16* g, __hip_bfloat16* l) {
    __builtin_amdgcn_global_load_lds(
        (const __attribute__((address_space(1))) unsigned int*)g,
        (__attribute__((address_space(3))) unsigned int*)l,
        16, 0, 0);
}

// ---------------- merged prep: all f32->bf16 converts + RoPE cos/sin table ----------------
__global__ void prep_kernel(const float* __restrict__ x,  const float* __restrict__ Wq,
                            const float* __restrict__ Wk, const float* __restrict__ Wv,
                            const float* __restrict__ Wo,
                            __hip_bfloat16* __restrict__ xb, __hip_bfloat16* __restrict__ wcat,
                            __hip_bfloat16* __restrict__ wob, float2* __restrict__ ropeTab) {
    int tid = blockIdx.x * blockDim.x + threadIdx.x;
    const int CVT_THREADS = 4718592;
    if (tid < CVT_THREADS) {
        int i4 = tid * 4;
        const float* src;
        __hip_bfloat16* dst;
        int off;
        if (i4 < 8388608)       { src = x;  dst = xb;             off = i4; }
        else if (i4 < 12582912) { src = Wq; dst = wcat;           off = i4 - 8388608; }
        else if (i4 < 13631488) { src = Wk; dst = wcat + 4194304; off = i4 - 12582912; }
        else if (i4 < 14680064) { src = Wv; dst = wcat + 5242880; off = i4 - 13631488; }
        else                    { src = Wo; dst = wob;            off = i4 - 14680064; }
        float4 v = *reinterpret_cast<const float4*>(src + off);
        short4 o;
        o.x = f2bs(v.x); o.y = f2bs(v.y); o.z = f2bs(v.z); o.w = f2bs(v.w);
        *reinterpret_cast<short4*>(dst + off) = o;
    } else {
        int e = tid - CVT_THREADS;
        if (e < 131072) {
            int t = e >> 6, p = e & 63;
            float inv = __expf(-(float)p * (9.210340371976184f / 64.0f));  // 10000^(-p/64)
            float ang = (float)t * inv;
            ropeTab[e] = make_float2(cosf(ang), sinf(ang));
        }
    }
}

// ---------------- GEMM1 (m97 structure) with fused RoPE + q/k/v scatter epilogue ----------------
// PROVEN 78.0 us (R3/R6). Untouched.
__global__ __launch_bounds__(256) void gemm_qkv(const __hip_bfloat16* __restrict__ A,
                                                const __hip_bfloat16* __restrict__ Bm,
                                                const float2* __restrict__ ropeTab,
                                                __hip_bfloat16* __restrict__ qo,
                                                __hip_bfloat16* __restrict__ ko,
                                                __hip_bfloat16* __restrict__ vT) {
    const int K = 2048;
    __shared__ __hip_bfloat16 As[128 * 32];
    __shared__ __hip_bfloat16 Bs[128 * 32];
    const int tid  = threadIdx.x;
    const int lane = tid & 63;
    const int wv   = tid >> 6;
    const int m0 = blockIdx.y * 128, n0 = blockIdx.x * 128;
    const int wm = (wv >> 1) * 64, wn = (wv & 1) * 64;
    const int q16 = lane >> 4, r16 = lane & 15;

    f32x4 acc[4][4] = {};

    const int lrow = tid >> 2;
    const int lcol = (tid & 3) * 8;
    const __hip_bfloat16* aG = A  + (size_t)(m0 + lrow) * K + lcol;
    const __hip_bfloat16* bG = Bm + (size_t)(n0 + lrow) * K + lcol;
    __hip_bfloat16* aL = As + tid * 8;
    __hip_bfloat16* bL = Bs + tid * 8;

    for (int k0 = 0; k0 < K; k0 += 32) {
        __syncthreads();
        gl_lds16(aG + k0,          aL);
        gl_lds16(aG + 64 * K + k0, aL + 2048);
        gl_lds16(bG + k0,          bL);
        gl_lds16(bG + 64 * K + k0, bL + 2048);
        __syncthreads();
        bf16x8 af[4], bfr[4];
#pragma unroll
        for (int i = 0; i < 4; i++)
            af[i] = *reinterpret_cast<const bf16x8*>(As + (wm + i * 16 + r16) * 32 + q16 * 8);
#pragma unroll
        for (int j = 0; j < 4; j++)
            bfr[j] = *reinterpret_cast<const bf16x8*>(Bs + (wn + j * 16 + r16) * 32 + q16 * 8);
#pragma unroll
        for (int i = 0; i < 4; i++)
#pragma unroll
            for (int j = 0; j < 4; j++)
                acc[i][j] = __builtin_amdgcn_mfma_f32_16x16x32_bf16(af[i], bfr[j], acc[i][j], 0, 0, 0);
    }

    const int hb = n0 >> 7;   // 0..15 q-head | 16..19 k-head | 20..23 v-head (block-uniform)
    const float sgn = (r16 & 1) ? 1.0f : -1.0f;
#pragma unroll
    for (int i = 0; i < 4; i++)
#pragma unroll
        for (int r = 0; r < 4; r++) {
            const int m = m0 + wm + i * 16 + q16 * 4 + r;
            const int b = m >> 11, t = m & 2047;
            if (hb < 20) {  // q or k: RoPE then scatter
                const float2* tabRow = ropeTab + t * 64;
                __hip_bfloat16* dst = (hb < 16)
                    ? qo + ((size_t)(b * NH_ + hb) * T_ + t) * D_
                    : ko + ((size_t)(b * NKV_ + (hb - 16)) * T_ + t) * D_;
#pragma unroll
                for (int j = 0; j < 4; j++) {
                    const int dloc = wn + j * 16 + r16;
                    float v = acc[i][j][r];
                    float prt = __shfl_xor(v, 1);
                    float2 cs = tabRow[dloc >> 1];
                    float res = fmaf(prt * sgn, cs.y, v * cs.x);
                    dst[dloc] = __float2bfloat16(res);
                }
            } else {        // v: no rope, transposed (d, t) store
                __hip_bfloat16* dst = vT + (size_t)(b * NKV_ + (hb - 20)) * D_ * T_ + t;
#pragma unroll
                for (int j = 0; j < 4; j++) {
                    const int d = wn + j * 16 + r16;
                    dst[(size_t)d * T_] = __float2bfloat16(acc[i][j][r]);
                }
            }
        }
}

// ---------------- 256xBNxK64 free-flow bf16 GEMM, C = A @ B^T (GEMM2) ----------------
template <int MODE, int BN, int NTN>
__global__ __launch_bounds__(512, 2) void gemm_ff(
    const __hip_bfloat16* __restrict__ A,
    const __hip_bfloat16* __restrict__ Bm,
    float* __restrict__ Cout) {
    constexpr int K = 2048;
    constexpr int NT = K / 64;
    constexpr int WN = BN / 64;
    constexpr int WM = 8 / WN;
    constexpr int RPW = 256 / WM;
    constexpr int MI_T = RPW / 16;
    constexpr int BSZ = BN * 64;
    constexpr int BLOADS = BSZ / 8192;
    extern __shared__ char lds[];

    const int tid = threadIdx.x;
    const int lane = tid & 63;
    const int wid = tid >> 6;
    const int wm = wid / WN, wn = wid % WN;
    const int q16 = lane >> 4, r16 = lane & 15;

    const int cpx = (int)gridDim.x >> 3;
    const int bs = ((int)blockIdx.x & 7) * cpx + ((int)blockIdx.x >> 3);
    const int tm = bs / NTN, tn = bs % NTN;
    const int rmA = tm * 256, rmB = tn * BN;

    const int csw = (q16 << 4) ^ ((r16 & 3) << 4);

    f32x4 acc[MI_T][4] = {};
    bf16x8 aF[MI_T], bF[4];

#define STG_A(buf_, sl_, kstep_)                                                     \
    { _Pragma("unroll") for (int li = 0; li < 2; li++) {                             \
        const int L_ = li * 8192 + tid * 16;                                         \
        const int rw_ = L_ >> 6;                                                     \
        const int cb_ = (L_ & 63) ^ ((rw_ & 3) << 4);                                \
        gl_lds16(A + (size_t)(rmA + rw_) * K + (kstep_) * 64 + (sl_) * 32 + (cb_ >> 1), \
                 (__hip_bfloat16*)(lds + (buf_) * 32768 + (sl_) * 16384 + L_));      \
    } }
#define STG_B(buf_, sl_, kstep_)                                                     \
    { _Pragma("unroll") for (int li = 0; li < BLOADS; li++) {                        \
        const int L_ = li * 8192 + tid * 16;                                         \
        const int rw_ = L_ >> 6;                                                     \
        const int cb_ = (L_ & 63) ^ ((rw_ & 3) << 4);                                \
        gl_lds16(Bm + (size_t)(rmB + rw_) * K + (kstep_) * 64 + (sl_) * 32 + (cb_ >> 1), \
                 (__hip_bfloat16*)(lds + 65536 + (buf_) * 2 * BSZ + (sl_) * BSZ + L_)); \
    } }
#define RD_A(buf_, sl_)                                                              \
    { _Pragma("unroll") for (int mi = 0; mi < MI_T; mi++)                            \
        aF[mi] = *(const bf16x8*)(lds + (buf_) * 32768 + (sl_) * 16384 +             \
                                  (wm * RPW + mi * 16 + r16) * 64 + csw); }
#define RD_B(buf_, sl_)                                                              \
    { _Pragma("unroll") for (int bi = 0; bi < 4; bi++)                               \
        bF[bi] = *(const bf16x8*)(lds + 65536 + (buf_) * 2 * BSZ + (sl_) * BSZ +     \
                                  (wn * 64 + bi * 16 + r16) * 64 + csw); }
#define MM_                                                                          \
    { __builtin_amdgcn_s_setprio(1);                                                 \
      _Pragma("unroll") for (int mi = 0; mi < MI_T; mi++)                            \
      _Pragma("unroll") for (int bi = 0; bi < 4; bi++)                               \
          acc[mi][bi] = __builtin_amdgcn_mfma_f32_16x16x32_bf16(                     \
              aF[mi], bF[bi], acc[mi][bi], 0, 0, 0);                                 \
      __builtin_amdgcn_s_setprio(0); }
#define VMC                                                                          \
    { if constexpr (BLOADS == 2) { asm volatile("s_waitcnt vmcnt(4)" ::: "memory"); } \
      else                       { asm volatile("s_waitcnt vmcnt(3)" ::: "memory"); } }
#define BAR __builtin_amdgcn_s_barrier()

    STG_A(0, 0, 0); STG_B(0, 0, 0);
    STG_A(0, 1, 0); STG_B(0, 1, 0);
    VMC; BAR;

    for (int u = 0; u < NT - 1; u++) {
        const int bf_ = u & 1;
        RD_A(bf_, 0); RD_B(bf_, 0);
        STG_A(bf_ ^ 1, 0, u + 1); STG_B(bf_ ^ 1, 0, u + 1);
        MM_;
        VMC; BAR;
        RD_A(bf_, 1); RD_B(bf_, 1);
        STG_A(bf_ ^ 1, 1, u + 1); STG_B(bf_ ^ 1, 1, u + 1);
        MM_;
        VMC; BAR;
    }
    {
        const int bf_ = (NT - 1) & 1;
        RD_A(bf_, 0); RD_B(bf_, 0);
        MM_;
        asm volatile("s_waitcnt vmcnt(0)" ::: "memory"); BAR;
        RD_A(bf_, 1); RD_B(bf_, 1);
        MM_;
    }
#undef BAR
#undef VMC
#undef MM_
#undef RD_B
#undef RD_A
#undef STG_B
#undef STG_A

    if constexpr (MODE == 0) {
        constexpr int N = NTN * BN;
        float* const cbase = Cout + (size_t)(rmA + wm * RPW) * N + tn * BN + wn * 64 + r16;
#pragma unroll
        for (int mi = 0; mi < MI_T; mi++)
#pragma unroll
            for (int r = 0; r < 4; r++) {
                float* dst = cbase + (size_t)(mi * 16 + q16 * 4 + r) * N;
#pragma unroll
                for (int bi = 0; bi < 4; bi++)
                    dst[bi * 16] = acc[mi][bi][r];
            }
    }
}

// ---------------- flash attention, GQA-cooperative, split-s, in-place PV, balanced ----------------
// R8 changes vs R6:
// 1) PV via 2x mfma_f32_16x16x16bf16_1k (K=16): the score C-layout (lane(q16,r16)
//    holds P[q=r16][s=4q16+r]; sc1 -> +16) IS the 16x16x16 A-operand layout
//    (lane holds A[row=l&15][k=(l>>4)*4+j]) — P is consumed fully in-register,
//    no LDS round-trip, no cross-lane movement. (R7's single-shfl redistribution
//    was provably impossible: two dest groups read the same source lane needing
//    different registers.) V B-fragments: lane needs V[s=4q16+j][d=r16], which in
//    the Vs chunk layout (short idx 128*(t>>3)+8*d+(t&7)) is the contiguous b64 at
//    (q16>>1)*128 + r16*8 + (q16&1)*4, hi half at +256. Falls back to the proven
//    Pl-LDS path if the builtin is unavailable.
// 2) Triple-balanced x-mapping: CU triple {a,a+32,a+64} (256 mod 96 = 64) gets
//    weights (a+1) + 32 + (32-a) = 65 iterations exactly (was 34..96).
__global__ __launch_bounds__(256, 3) void attn_kernel(const __hip_bfloat16* __restrict__ Q,
                                                      const __hip_bfloat16* __restrict__ Kt,
                                                      const __hip_bfloat16* __restrict__ Vt,
                                                      __hip_bfloat16* __restrict__ Ao,
                                                      float* __restrict__ O0,
                                                      float* __restrict__ O1,
                                                      float* __restrict__ l0p,
                                                      float* __restrict__ l1p) {
    __shared__ __hip_bfloat16 Ks[2][4096];   // 8 chunks x 512 shorts, x2 buffers
    __shared__ __hip_bfloat16 Vs[2][4096];
#if !HAVE_MFMA16
    __shared__ __hip_bfloat16 Pl[4][1280];
#endif

    const int lane = threadIdx.x & 63, wv = threadIdx.x >> 6;
    const int bg = blockIdx.y;                              // 0..7 : (b,g)
    const int xb_ = (int)blockIdx.x;                        // 0..95 work unit
    int tb, nIt, sIdx;
    if (xb_ < 32)      { tb = xb_;       nIt = xb_ + 1;  sIdx = -1; }  // unsplit
    else if (xb_ < 64) { tb = 95 - xb_;  nIt = 32;       sIdx = 0;  }  // s in [0,1024)
    else               { tb = 127 - xb_; nIt = 96 - xb_; sIdx = 1;  }  // s in [1024,...)
    const int sBase = (sIdx == 1) ? 1024 : 0;
    const int b = bg >> 2, g = bg & 3;
    const int h = g * 4 + wv;                               // this wave's q-head
    const int t0 = tb * 32;
    const int q16 = lane >> 4, r16 = lane & 15;

    const __hip_bfloat16* qh = Q + ((size_t)((b * NH_ + h) * T_) + t0) * D_;
    const __hip_bfloat16* kh = Kt + (size_t)(b * NKV_ + g) * T_ * D_;
    const __hip_bfloat16* vh = Vt + (size_t)(b * NKV_ + g) * D_ * T_;

    bf16x8 bqA[4], bqB[4];
#pragma unroll
    for (int kk = 0; kk < 4; kk++) {
        bqA[kk] = *reinterpret_cast<const bf16x8*>(qh + (size_t)r16 * D_ + kk * 32 + q16 * 8);
        bqB[kk] = *reinterpret_cast<const bf16x8*>(qh + (size_t)(16 + r16) * D_ + kk * 32 + q16 * 8);
    }

    float liA = 0.f, liB = 0.f;
    f32x4 oA[8], oB[8];
#pragma unroll
    for (int d = 0; d < 8; d++) {
        oA[d] = (f32x4){0.f, 0.f, 0.f, 0.f};
        oB[d] = (f32x4){0.f, 0.f, 0.f, 0.f};
    }

    const float SCL2 = 0.088388347648318447f * 1.4426950408889634f;  // (1/sqrt(D)) * log2(e)
    const int tqA = t0 + r16;
    const int tqB = t0 + 16 + r16;
#if HAVE_MFMA16
    const int vIdx = (q16 >> 1) * 128 + r16 * 8 + (q16 & 1) * 4;  // shorts, within chunk
#endif

    const __hip_bfloat16* gK = kh + (size_t)((wv & 1) * 16 + r16) * D_ + q16 * 8;
    const __hip_bfloat16* gV = vh + (size_t)(((wv - 2) * 4) * 16 + r16) * T_ + q16 * 8;

#define STAGE(bufi, s0_)                                                        \
    do {                                                                        \
        if (wv < 2) {                                                           \
            const __hip_bfloat16* gp = gK + (size_t)(s0_) * D_;                 \
            __hip_bfloat16* lp = &Ks[bufi][(wv * 4) * 512] + lane * 8;          \
            gl_lds16(gp,      lp);                                              \
            gl_lds16(gp + 32, lp + 512);                                        \
            gl_lds16(gp + 64, lp + 1024);                                       \
            gl_lds16(gp + 96, lp + 1536);                                       \
        } else {                                                                \
            const __hip_bfloat16* gp = gV + (s0_);                              \
            __hip_bfloat16* lp = &Vs[bufi][((wv - 2) * 4) * 512] + lane * 8;    \
            gl_lds16(gp,                      lp);                              \
            gl_lds16(gp + (size_t)16 * T_,    lp + 512);                        \
            gl_lds16(gp + (size_t)32 * T_,    lp + 1024);                       \
            gl_lds16(gp + (size_t)48 * T_,    lp + 1536);                       \
        }                                                                       \
    } while (0)

    STAGE(0, sBase);

    for (int j = 0; j < nIt; j++) {
        const int s0 = sBase + j * 32;
        const int cur = j & 1;
        __syncthreads();  // staging of `cur` complete; buffer `cur^1` free
        if (j + 1 < nIt) STAGE(cur ^ 1, s0 + 32);

        f32x4 sc0A = (f32x4){0.f, 0.f, 0.f, 0.f};
        f32x4 sc1A = (f32x4){0.f, 0.f, 0.f, 0.f};
        f32x4 sc0B = (f32x4){0.f, 0.f, 0.f, 0.f};
        f32x4 sc1B = (f32x4){0.f, 0.f, 0.f, 0.f};
        {
            bf16x8 ak[4];
#pragma unroll
            for (int kk = 0; kk < 4; kk++)
                ak[kk] = *reinterpret_cast<const bf16x8*>(&Ks[cur][kk * 512] + lane * 8);
#pragma unroll
            for (int kk = 0; kk < 4; kk++) {
                sc0A = __builtin_amdgcn_mfma_f32_16x16x32_bf16(ak[kk], bqA[kk], sc0A, 0, 0, 0);
                sc0B = __builtin_amdgcn_mfma_f32_16x16x32_bf16(ak[kk], bqB[kk], sc0B, 0, 0, 0);
            }
#pragma unroll
            for (int kk = 0; kk < 4; kk++)
                ak[kk] = *reinterpret_cast<const bf16x8*>(&Ks[cur][(4 + kk) * 512] + lane * 8);
#pragma unroll
            for (int kk = 0; kk < 4; kk++) {
                sc1A = __builtin_amdgcn_mfma_f32_16x16x32_bf16(ak[kk], bqA[kk], sc1A, 0, 0, 0);
                sc1B = __builtin_amdgcn_mfma_f32_16x16x32_bf16(ak[kk], bqB[kk], sc1B, 0, 0, 0);
            }
        }

        // softmax (m=0): exp in place over score regs
        float psA = 0.f, psB = 0.f;
        if (s0 + 32 > t0) {  // diagonal iteration: causal mask (wave-uniform branch)
#pragma unroll
            for (int r = 0; r < 4; r++) {
                int s_a = s0 + q16 * 4 + r;
                sc0A[r] = (s_a <= tqA)      ? __builtin_amdgcn_exp2f(sc0A[r] * SCL2) : 0.f;
                sc1A[r] = (s_a + 16 <= tqA) ? __builtin_amdgcn_exp2f(sc1A[r] * SCL2) : 0.f;
                sc0B[r] = (s_a <= tqB)      ? __builtin_amdgcn_exp2f(sc0B[r] * SCL2) : 0.f;
                sc1B[r] = (s_a + 16 <= tqB) ? __builtin_amdgcn_exp2f(sc1B[r] * SCL2) : 0.f;
                psA += sc0A[r] + sc1A[r];
                psB += sc0B[r] + sc1B[r];
            }
        } else {  // interior iteration
#pragma unroll
            for (int r = 0; r < 4; r++) {
                sc0A[r] = __builtin_amdgcn_exp2f(sc0A[r] * SCL2);
                sc1A[r] = __builtin_amdgcn_exp2f(sc1A[r] * SCL2);
                sc0B[r] = __builtin_amdgcn_exp2f(sc0B[r] * SCL2);
                sc1B[r] = __builtin_amdgcn_exp2f(sc1B[r] * SCL2);
                psA += sc0A[r] + sc1A[r];
                psB += sc0B[r] + sc1B[r];
            }
        }
        liA += psA;
        liB += psB;

#if HAVE_MFMA16
        // P consumed in place: convert the 4 score quads to bf16x4 A-fragments
        bf16x4 pf0A, pf1A, pf0B, pf1B;
#pragma unroll
        for (int r = 0; r < 4; r++) {
            pf0A[r] = f2bs(sc0A[r]);
            pf1A[r] = f2bs(sc1A[r]);
            pf0B[r] = f2bs(sc0B[r]);
            pf1B[r] = f2bs(sc1B[r]);
        }
        const __hip_bfloat16* vbase = &Vs[cur][vIdx];
#pragma unroll
        for (int d = 0; d < 8; d++) {
            bf16x4 bvlo = *reinterpret_cast<const bf16x4*>(vbase + d * 512);
            bf16x4 bvhi = *reinterpret_cast<const bf16x4*>(vbase + d * 512 + 256);
            oA[d] = MFMA16(pf0A, bvlo, oA[d]);
            oA[d] = MFMA16(pf1A, bvhi, oA[d]);
            oB[d] = MFMA16(pf0B, bvlo, oB[d]);
            oB[d] = MFMA16(pf1B, bvhi, oB[d]);
        }
#else
        // fallback: proven Pl LDS round-trip (R6)
        ushort4 w0A, w1A, w0B, w1B;
#pragma unroll
        for (int r = 0; r < 4; r++) {
            ((unsigned short*)&w0A)[r] = (unsigned short)f2bs(sc0A[r]);
            ((unsigned short*)&w1A)[r] = (unsigned short)f2bs(sc1A[r]);
            ((unsigned short*)&w0B)[r] = (unsigned short)f2bs(sc0B[r]);
            ((unsigned short*)&w1B)[r] = (unsigned short)f2bs(sc1B[r]);
        }
        *reinterpret_cast<ushort4*>(&Pl[wv][r16 * 40 + q16 * 4]) = w0A;
        *reinterpret_cast<ushort4*>(&Pl[wv][r16 * 40 + 16 + q16 * 4]) = w1A;
        *reinterpret_cast<ushort4*>(&Pl[wv][640 + r16 * 40 + q16 * 4]) = w0B;
        *reinterpret_cast<ushort4*>(&Pl[wv][640 + r16 * 40 + 16 + q16 * 4]) = w1B;
        asm volatile("s_waitcnt lgkmcnt(0)" ::: "memory");
        bf16x8 pfA = *reinterpret_cast<const bf16x8*>(&Pl[wv][r16 * 40 + q16 * 8]);
        bf16x8 pfB = *reinterpret_cast<const bf16x8*>(&Pl[wv][640 + r16 * 40 + q16 * 8]);
#pragma unroll
        for (int d = 0; d < 8; d++) {
            bf16x8 bv = *reinterpret_cast<const bf16x8*>(&Vs[cur][d * 512] + lane * 8);
            oA[d] = __builtin_amdgcn_mfma_f32_16x16x32_bf16(pfA, bv, oA[d], 0, 0, 0);
            oB[d] = __builtin_amdgcn_mfma_f32_16x16x32_bf16(pfB, bv, oB[d], 0, 0, 0);
        }
#endif
    }

    liA += __shfl_xor(liA, 16);
    liA += __shfl_xor(liA, 32);
    liB += __shfl_xor(liB, 16);
    liB += __shfl_xor(liB, 32);

    if (sIdx < 0) {
#pragma unroll
        for (int r = 0; r < 4; r++) {
            float lrA = __shfl(liA, q16 * 4 + r, 16);
            float lrB = __shfl(liB, q16 * 4 + r, 16);
            float invA = 1.0f / lrA;
            float invB = 1.0f / lrB;
            int tA = t0 + q16 * 4 + r;
            __hip_bfloat16* dstA = Ao + (size_t)(b * T_ + tA) * C_ + h * D_ + r16;
            __hip_bfloat16* dstB = dstA + (size_t)16 * C_;
#pragma unroll
            for (int d = 0; d < 8; d++) {
                dstA[d * 16] = __float2bfloat16(oA[d][r] * invA);
                dstB[d * 16] = __float2bfloat16(oB[d][r] * invB);
            }
        }
    } else {
        float* Os = (sIdx == 0) ? O0 : O1;
        float* ls = (sIdx == 0) ? l0p : l1p;
        const size_t rb = (size_t)(b * NH_ + h) * 1024 + (size_t)(t0 - 1024);
        if (q16 == 0) {
            ls[rb + r16]      = liA;
            ls[rb + 16 + r16] = liB;
        }
#pragma unroll
        for (int r = 0; r < 4; r++) {
            int rowl = q16 * 4 + r;
            float* dA = Os + (rb + rowl) * 128 + r16;
            float* dB = Os + (rb + 16 + rowl) * 128 + r16;
#pragma unroll
            for (int d = 0; d < 8; d++) {
                dA[d * 16] = oA[d][r];
                dB[d * 16] = oB[d][r];
            }
        }
    }
#undef STAGE
}

// ---------------- combine split-s partials (rows t >= 1024) ----------------
__global__ void attn_combine(const float* __restrict__ O0, const float* __restrict__ O1,
                             const float* __restrict__ l0, const float* __restrict__ l1,
                             __hip_bfloat16* __restrict__ Ao) {
    int idx = blockIdx.x * blockDim.x + threadIdx.x;   // [0, 32768*32)
    int row = idx >> 5, d4 = (idx & 31) << 2;
    int bh = row >> 10, tl = row & 1023;
    int b = bh >> 4, h = bh & 15;
    float inv = 1.0f / (l0[row] + l1[row]);
    float4 a = *reinterpret_cast<const float4*>(O0 + (size_t)row * 128 + d4);
    float4 c = *reinterpret_cast<const float4*>(O1 + (size_t)row * 128 + d4);
    short4 o;
    o.x = f2bs((a.x + c.x) * inv);
    o.y = f2bs((a.y + c.y) * inv);
    o.z = f2bs((a.z + c.z) * inv);
    o.w = f2bs((a.w + c.w) * inv);
    *reinterpret_cast<short4*>(Ao + (size_t)(b * T_ + 1024 + tl) * C_ + h * D_ + d4) = o;
}

// ---------------- launch ----------------
extern "C" void kernel_launch(void* const* d_in, const int* in_sizes, int n_in,
                              void* d_out, int out_size, void* d_ws, size_t ws_size,
                              hipStream_t stream) {
    const float* x  = (const float*)d_in[0];
    const float* Wq = (const float*)d_in[1];
    const float* Wk = (const float*)d_in[2];
    const float* Wv = (const float*)d_in[3];
    const float* Wo = (const float*)d_in[4];
    float* out = (float*)d_out;
    char* ws = (char*)d_ws;

    __hip_bfloat16* xb   = (__hip_bfloat16*)(ws + 0);          // 16.78 MB (dead after GEMM1)
    __hip_bfloat16* wcat = (__hip_bfloat16*)(ws + 16777216);   // 12.58 MB
    float2*         ropeTab = (float2*)(ws + 29360128);        // 1.05 MB
    __hip_bfloat16* wob  = (__hip_bfloat16*)(ws + 30408704);   // 8.39 MB (live until GEMM2)
    __hip_bfloat16* qatt = (__hip_bfloat16*)(ws + 38797312);   // 16.78 MB
    __hip_bfloat16* katt = (__hip_bfloat16*)(ws + 55574528);   // 4.19 MB
    __hip_bfloat16* vT   = (__hip_bfloat16*)(ws + 59768832);   // 4.19 MB
    __hip_bfloat16* aout = (__hip_bfloat16*)(ws + 63963136);   // 16.78 MB
    float* O0 = (float*)(ws + 0);                              // overlays dead xb
    float* O1 = (float*)(ws + 80740352);                       // 16.78 MB
    float* l0 = (float*)(ws + 97517568);                       // 128 KB
    float* l1 = (float*)(ws + 97648640);                       // 128 KB (end ~97.8 MB)

    static bool s_attr_done = false;
    if (!s_attr_done) {
        hipFuncSetAttribute(reinterpret_cast<const void*>(&gemm_ff<0, 128, 16>),
                            hipFuncAttributeMaxDynamicSharedMemorySize, 98304);
        s_attr_done = true;
    }

    const int thr = 256;
    prep_kernel<<<18944, thr, 0, stream>>>(x, Wq, Wk, Wv, Wo, xb, wcat, wob, ropeTab);

    // QKV projection + RoPE + scatter: m97 structure, grid 24x32 = 768 blocks
    gemm_qkv<<<dim3(24, 32), 256, 0, stream>>>(xb, wcat, ropeTab, qatt, katt, vT);

    attn_kernel<<<dim3(96, 8), 256, 0, stream>>>(qatt, katt, vT, aout, O0, O1, l0, l1);
    attn_combine<<<(2 * NH_ * 1024 * 32) / thr, thr, 0, stream>>>(O0, O1, l0, l1, aout);

    // Output projection: M=4096, N=2048 (BN=128 -> 16 tn), grid 256
    gemm_ff<0, 128, 16><<<256, 512, 98304, stream>>>(aout, wob, out);
}